// Round 16
// baseline (375.398 us; speedup 1.0000x reference)
//
#include <hip/hip_runtime.h>
#include <hip/hip_bf16.h>
#include <math.h>

#define B_SZ 2
#define SEQ  8192
#define DM   512
#define DI   1024
#define DS   16
#define DTR  32
#define M_TOT (B_SZ*SEQ)        // 16384 positions
#define LOG2E 1.44269504088896f
#define NCHAN  (4*DI*DS)        // 65536 scan channels ((dir*2+b)*DI+e)*DS+n
#define NG     (4*DI)           // 4096 (dir,b,e) groups
#define CLT    8                // conv timesteps per thread

typedef __attribute__((ext_vector_type(8))) short bf16x8;
typedef __attribute__((ext_vector_type(4))) float f32x4;
typedef __attribute__((ext_vector_type(2))) float f32x2;
typedef unsigned short u16;

__device__ __forceinline__ float bf2f(u16 u){
  union { unsigned u; float f; } v; v.u = ((unsigned)u) << 16; return v.f;
}
__device__ __forceinline__ u16 f2bf(float f){
  union { float f; unsigned u; } v; v.f = f;
  unsigned r = v.u + 0x7FFFu + ((v.u >> 16) & 1u);
  return (u16)(r >> 16);
}
__device__ __forceinline__ float silu_f(float x){ return x / (1.f + __expf(-x)); }
__device__ __forceinline__ float softplus_f(float x){
  return (x > 15.f) ? x : __logf(1.f + __expf(x));
}
__device__ __forceinline__ float fexp2(float x){ return __builtin_amdgcn_exp2f(x); }

__device__ __forceinline__ void dA_generic(float d, const float* A2, float* dAv){
  #pragma unroll
  for (int n = 0; n < DS; n++) dAv[n] = fexp2(A2[n] * d);
}

// ---------------------------------------------------------------------------
// f32 -> bf16 bulk convert, 8 elems/thread.
// ---------------------------------------------------------------------------
__global__ __launch_bounds__(256) void cvt_k(
    const float* __restrict__ s, u16* __restrict__ d)
{
  const size_t i = (size_t)blockIdx.x * 256 + threadIdx.x;
  const float4 a = ((const float4*)s)[i * 2];
  const float4 b = ((const float4*)s)[i * 2 + 1];
  union { uint4 v; u16 h[8]; } o;
  o.h[0] = f2bf(a.x); o.h[1] = f2bf(a.y); o.h[2] = f2bf(a.z); o.h[3] = f2bf(a.w);
  o.h[4] = f2bf(b.x); o.h[5] = f2bf(b.y); o.h[6] = f2bf(b.z); o.h[7] = f2bf(b.w);
  ((uint4*)d)[i] = o.v;
}

// Packed weight convert: 6 tensors -> one bf16 arena. Unit = 8 elems.
#define WU_INW  131072
#define WU_XW   8192
#define WU_DTW  4096
#define WU_OUTW 65536
#define WU_TOT  (WU_INW + 2*WU_XW + 2*WU_DTW + WU_OUTW)   // 221184
__global__ __launch_bounds__(256) void cvtw_k(
    const float* __restrict__ inw, const float* __restrict__ xwf,
    const float* __restrict__ xwr, const float* __restrict__ dtwf,
    const float* __restrict__ dtwr, const float* __restrict__ outw,
    u16* __restrict__ dst)
{
  int i = blockIdx.x * 256 + threadIdx.x;
  const float* s;
  int base = 0;
  if (i < WU_INW) { s = inw; }
  else if ((i -= WU_INW) < WU_XW) { s = xwf; base = WU_INW; }
  else if ((i -= WU_XW) < WU_XW)  { s = xwr; base = WU_INW + WU_XW; }
  else if ((i -= WU_XW) < WU_DTW) { s = dtwf; base = WU_INW + 2*WU_XW; }
  else if ((i -= WU_DTW) < WU_DTW){ s = dtwr; base = WU_INW + 2*WU_XW + WU_DTW; }
  else { i -= WU_DTW; s = outw; base = WU_INW + 2*WU_XW + 2*WU_DTW; }
  const float4 a = ((const float4*)s)[i * 2];
  const float4 b = ((const float4*)s)[i * 2 + 1];
  union { uint4 v; u16 h[8]; } o;
  o.h[0] = f2bf(a.x); o.h[1] = f2bf(a.y); o.h[2] = f2bf(a.z); o.h[3] = f2bf(a.w);
  o.h[4] = f2bf(b.x); o.h[5] = f2bf(b.y); o.h[6] = f2bf(b.z); o.h[7] = f2bf(b.w);
  ((uint4*)(dst))[base + i] = o.v;
}

// ---------------------------------------------------------------------------
// MFMA bf16 GEMM, global_load_lds staging + XOR swizzle, templated BK.
// EPI: 0 = split xz; 1 = bf16 + f32 side-store n>=32; 2 = softplus+bias; 3 = f32
// ---------------------------------------------------------------------------
template<int BN, int BK, int EPI, bool DUAL>
__global__ __launch_bounds__(256) void gemm_k(
    const u16* __restrict__ Ap,  const u16* __restrict__ Ap2, int lda,
    const u16* __restrict__ Bw,  const u16* __restrict__ Bw2, int K,
    void* __restrict__ out0, void* __restrict__ out02,
    void* __restrict__ out1, void* __restrict__ out12,
    const float* __restrict__ bias, const float* __restrict__ bias2, int ldo)
{
  constexpr int BM = 128;
  constexpr int NSLOT = BK / 8;        // 16B slots per LDS row
  constexpr int RPI   = 512 / BK;      // rows covered by one 1KB wave-issue
  __shared__ __align__(16) u16 As[BM * BK];
  __shared__ __align__(16) u16 Bs[BN * BK];
  const int tid  = threadIdx.x;
  const int lane = tid & 63, wid = tid >> 6;
  const int mt = blockIdx.x, nt = blockIdx.y;
  const int z  = DUAL ? blockIdx.z : 0;
  const u16* A = z ? Ap2 : Ap;
  const u16* W = z ? Bw2 : Bw;
  void* o0 = z ? out02 : out0;
  void* o1 = z ? out12 : out1;
  const float* bi = z ? bias2 : bias;

  constexpr int FM = (BN == 128) ? 4 : 2;
  const int wm = (BN == 128) ? ((wid >> 1) * 64) : (wid * 32);
  const int wn = (BN == 128) ? ((wid & 1) * 64) : 0;

  f32x4 acc[FM][4];
  #pragma unroll
  for (int i = 0; i < FM; i++)
    #pragma unroll
    for (int j = 0; j < 4; j++)
      acc[i][j] = (f32x4){0.f, 0.f, 0.f, 0.f};

  const int sr   = lane / NSLOT;                 // row within RPI-row chunk
  const int slot = lane % NSLOT;
  const int skey = (BK == 32) ? ((sr >> 1) & 3) : (sr & 7);
  const int sc   = (slot ^ skey) * 8;            // pre-swizzled source col

  for (int k0 = 0; k0 < K; k0 += BK) {
    #pragma unroll
    for (int j = 0; j < BM / RPI / 4; j++) {     // A issues per wave
      const int chunk = wid * (BM / RPI / 4) + j;
      const u16* src = A + (size_t)(mt * BM + chunk * RPI + sr) * lda + (k0 + sc);
      __builtin_amdgcn_global_load_lds(
          (const __attribute__((address_space(1))) void*)src,
          (__attribute__((address_space(3))) void*)(As + chunk * 512), 16, 0, 0);
    }
    #pragma unroll
    for (int j = 0; j < BN / RPI / 4; j++) {     // B issues per wave
      const int chunk = wid * (BN / RPI / 4) + j;
      const u16* src = W + (size_t)(nt * BN + chunk * RPI + sr) * K + (k0 + sc);
      __builtin_amdgcn_global_load_lds(
          (const __attribute__((address_space(1))) void*)src,
          (__attribute__((address_space(3))) void*)(Bs + chunk * 512), 16, 0, 0);
    }
    __syncthreads();

    const int row  = lane & 15;
    const int rkey = (BK == 32) ? ((row >> 1) & 3) : (row & 7);
    #pragma unroll
    for (int kh = 0; kh < BK / 32; kh++) {
      const int sl = (kh * 4 + (lane >> 4)) ^ rkey;   // swizzled 16B slot
      bf16x8 af[FM], bfr[4];
      #pragma unroll
      for (int i = 0; i < FM; i++)
        af[i] = *(const bf16x8*)&As[(wm + i * 16 + row) * BK + sl * 8];
      #pragma unroll
      for (int j = 0; j < 4; j++)
        bfr[j] = *(const bf16x8*)&Bs[(wn + j * 16 + row) * BK + sl * 8];
      #pragma unroll
      for (int i = 0; i < FM; i++)
        #pragma unroll
        for (int j = 0; j < 4; j++)
          acc[i][j] = __builtin_amdgcn_mfma_f32_16x16x32_bf16(af[i], bfr[j], acc[i][j], 0, 0, 0);
    }
    __syncthreads();
  }

  const int rb4 = (lane >> 4) * 4, col = lane & 15;
  #pragma unroll
  for (int i = 0; i < FM; i++) {
    #pragma unroll
    for (int j = 0; j < 4; j++) {
      #pragma unroll
      for (int r = 0; r < 4; r++) {
        const int m = mt * BM + wm + i * 16 + rb4 + r;
        const int n = nt * BN + wn + j * 16 + col;
        const float v = acc[i][j][r];
        if (EPI == 0) {
          if (n < DI) ((u16*)o0)[(size_t)m * DI + n] = f2bf(v);
          else        ((u16*)out1)[(size_t)m * DI + (n - DI)] = f2bf(silu_f(v));
        } else if (EPI == 1) {
          ((u16*)o0)[(size_t)m * ldo + n] = f2bf(v);
          if (n >= 32) ((float*)o1)[(size_t)m * 32 + (n - 32)] = v;
        } else if (EPI == 2) {
          ((u16*)o0)[(size_t)m * ldo + n] = f2bf(softplus_f(v + bi[n]));
        } else {
          ((float*)o0)[(size_t)m * ldo + n] = v;
        }
      }
    }
  }
}

// ---------------------------------------------------------------------------
// Depthwise causal conv(4) + bias + silu, BOTH directions in one ascending pass.
// ---------------------------------------------------------------------------
__global__ __launch_bounds__(256) void conv2_k(
    const u16* __restrict__ xpre,
    const float* __restrict__ wf, const float* __restrict__ bf_,
    const float* __restrict__ wr, const float* __restrict__ br_,
    u16* __restrict__ xf, u16* __restrict__ xr)
{
  const int tid  = threadIdx.x;
  const int et   = tid & 127;
  const int lsub = tid >> 7;
  const int e0 = et * 8;
  const int b  = blockIdx.y;
  const int l0 = (blockIdx.x * 2 + lsub) * CLT;
  const size_t base = (size_t)b * SEQ * DI + e0;

  float4 wf4[8], wr4[8];
  float  bfv[8], brv[8];
  #pragma unroll
  for (int j = 0; j < 8; j++) {
    wf4[j] = *(const float4*)(wf + (e0 + j) * 4);
    wr4[j] = *(const float4*)(wr + (e0 + j) * 4);
    bfv[j] = bf_[e0 + j];
    brv[j] = br_[e0 + j];
  }

  float c0[8], c1[8], c2[8];
  auto loadv = [&](int l, float* dst) {
    if (l < 0 || l >= SEQ) {
      #pragma unroll
      for (int j = 0; j < 8; j++) dst[j] = 0.f;
      return;
    }
    union { uint4 v; u16 s[8]; } t;
    t.v = *(const uint4*)(xpre + base + (size_t)l * DI);
    #pragma unroll
    for (int j = 0; j < 8; j++) dst[j] = bf2f(t.s[j]);
  };
  loadv(l0 - 3, c0); loadv(l0 - 2, c1); loadv(l0 - 1, c2);

  #pragma unroll
  for (int i = 0; i < CLT + 3; i++) {
    const int l = l0 + i;
    float cn[8];
    loadv(l, cn);
    if (i < CLT) {
      union { uint4 v; u16 s[8]; } o;
      #pragma unroll
      for (int j = 0; j < 8; j++) {
        const float v = bfv[j] + wf4[j].x * c0[j] + wf4[j].y * c1[j]
                               + wf4[j].z * c2[j] + wf4[j].w * cn[j];
        o.s[j] = f2bf(silu_f(v));
      }
      *(uint4*)(xf + base + (size_t)l * DI) = o.v;
    }
    if (i >= 3) {
      const int lr = l - 3;
      union { uint4 v; u16 s[8]; } o;
      #pragma unroll
      for (int j = 0; j < 8; j++) {
        const float v = brv[j] + wr4[j].w * c0[j] + wr4[j].z * c1[j]
                               + wr4[j].y * c2[j] + wr4[j].x * cn[j];
        o.s[j] = f2bf(silu_f(v));
      }
      *(uint4*)(xr + base + (size_t)(SEQ - 1 - lr) * DI) = o.v;
    }
    #pragma unroll
    for (int j = 0; j < 8; j++) { c0[j] = c1[j]; c1[j] = c2[j]; c2[j] = cn[j]; }
  }
}

// structured-A check + A20 for channel e
__device__ __forceinline__ bool a_check(const float* Al, int e, float& A20){
  float A2[DS];
  #pragma unroll
  for (int n = 0; n < DS; n++) A2[n] = -__expf(Al[e * DS + n]) * LOG2E;
  A20 = A2[0];
  bool st = true;
  #pragma unroll
  for (int n = 1; n < DS; n++)
    st = st && (fabsf(A2[n] - (float)(n + 1) * A20) <= 1e-3f * fabsf(A2[n]));
  return st;
}

// ---------------------------------------------------------------------------
// Big-path scan pass A: 1 channel/thread, f32 BC uniform loads, CT compile-time.
// grid: (8, nchunk, 4=dir*2+b), 128 thr
// ---------------------------------------------------------------------------
template<int CT_>
__global__ __launch_bounds__(128) void scanA2_k(
    const float* __restrict__ bcf, const float* __restrict__ bcr,
    const u16* __restrict__ xf_,   const u16* __restrict__ xr_,
    const float* __restrict__ Alf, const float* __restrict__ Alr,
    const u16* __restrict__ df_,   const u16* __restrict__ dr_,
    float* __restrict__ sumdP, float* __restrict__ bP)
{
  const int e = blockIdx.x * 128 + threadIdx.x;
  const int c = blockIdx.y;
  const int dir = blockIdx.z >> 1, b = blockIdx.z & 1;
  const float* bc = dir ? bcr : bcf;
  const u16* x    = dir ? xr_ : xf_;
  const float* Al = dir ? Alr : Alf;
  const u16* dpre = dir ? dr_ : df_;

  float A20;
  const bool structured = a_check(Al, e, A20);

  float sumd = 0.f;
  const size_t m0 = (size_t)b * SEQ + (size_t)c * CT_;
  const int g = (dir * 2 + b) * DI + e;
  const size_t cb = (size_t)c * NCHAN + (size_t)g * DS;

  if (structured) {
    f32x2 h2[8];
    #pragma unroll
    for (int k = 0; k < 8; k++) h2[k] = (f32x2){0.f, 0.f};
    #pragma unroll 2
    for (int t = 0; t < CT_; t++) {
      const size_t m = m0 + t;
      const float d  = bf2f(dpre[m * DI + e]);
      const float xv = bf2f(x[m * DI + e]);
      const float dbx = d * xv;
      sumd += d;
      const f32x4* bp = (const f32x4*)(bc + m * 32);
      const f32x4 b0 = bp[0], b1 = bp[1], b2 = bp[2], b3 = bp[3];
      const float q = fexp2(A20 * d), q2 = q * q, q4 = q2 * q2, q8 = q4 * q4;
      const f32x2 q2v = (f32x2){q2, q2}, q4v = (f32x2){q4, q4}, q8v = (f32x2){q8, q8};
      const f32x2 dbx2 = (f32x2){dbx, dbx};
      const f32x2 p0 = (f32x2){q, q2};
      const f32x2 p1 = p0 * q2v, p2 = p0 * q4v, p3 = p1 * q4v;
      const f32x2 p4 = p0 * q8v, p5 = p1 * q8v, p6 = p2 * q8v, p7 = p3 * q8v;
      h2[0] = p0 * h2[0] + dbx2 * (f32x2){b0[0], b0[1]};
      h2[1] = p1 * h2[1] + dbx2 * (f32x2){b0[2], b0[3]};
      h2[2] = p2 * h2[2] + dbx2 * (f32x2){b1[0], b1[1]};
      h2[3] = p3 * h2[3] + dbx2 * (f32x2){b1[2], b1[3]};
      h2[4] = p4 * h2[4] + dbx2 * (f32x2){b2[0], b2[1]};
      h2[5] = p5 * h2[5] + dbx2 * (f32x2){b2[2], b2[3]};
      h2[6] = p6 * h2[6] + dbx2 * (f32x2){b3[0], b3[1]};
      h2[7] = p7 * h2[7] + dbx2 * (f32x2){b3[2], b3[3]};
    }
    #pragma unroll
    for (int k = 0; k < 8; k++) *(f32x2*)&bP[cb + 2 * k] = h2[k];
  } else {
    float A2[DS], h[DS];
    #pragma unroll
    for (int n = 0; n < DS; n++) { A2[n] = -__expf(Al[e * DS + n]) * LOG2E; h[n] = 0.f; }
    for (int t = 0; t < CT_; t++) {
      const size_t m = m0 + t;
      const float d  = bf2f(dpre[m * DI + e]);
      const float xv = bf2f(x[m * DI + e]);
      const float dbx = d * xv;
      sumd += d;
      float dAv[DS];
      dA_generic(d, A2, dAv);
      #pragma unroll
      for (int n = 0; n < DS; n++)
        h[n] = dAv[n] * h[n] + dbx * bc[m * 32 + n];
    }
    #pragma unroll
    for (int n = 0; n < DS; n++) bP[cb + n] = h[n];
  }
  sumdP[(size_t)c * NG + g] = sumd;
}

// Scan pass B: cross-chunk scan, in place (bP becomes h_in per chunk).
__global__ __launch_bounds__(256) void scanB_k(
    const float* __restrict__ sumdP, float* __restrict__ bP,
    const float* __restrict__ Alog_f, const float* __restrict__ Alog_r, int nchunk)
{
  const int ch = blockIdx.x * 256 + threadIdx.x;   // 0..65535
  const int g = ch >> 4, n = ch & 15;
  const int dir = g >> 11, e = g & (DI - 1);
  const float* Al = dir ? Alog_r : Alog_f;
  const float A2 = -__expf(Al[e * DS + n]) * LOG2E;
  float h = 0.f;
  for (int c = 0; c < nchunk; c++) {
    const float a = fexp2(A2 * sumdP[(size_t)c * NG + g]);
    const size_t i = (size_t)c * NCHAN + ch;
    const float bb = bP[i];
    bP[i] = h;              // h_in for chunk c
    h = a * h + bb;
  }
}

// ---------------------------------------------------------------------------
// Big-path scan pass C, per-direction launches (DIR template):
//   DIR 0: yf[m] = y + x*D               (in place over x_f)
//   DIR 1: yf[mo] = (yf[mo] + y + x*D) * sz[mo]   (fused combine; mo flipped)
// dir0 launch must complete before dir1 (sequential on stream).
// grid: (8, nchunk, 2=b), 128 thr
// ---------------------------------------------------------------------------
template<int CT_, int DIR>
__global__ __launch_bounds__(128) void scanC2_k(
    const float* __restrict__ bcf, const float* __restrict__ bcr,
    const u16* __restrict__ xf_,   const u16* __restrict__ xr_,
    const float* __restrict__ Alf, const float* __restrict__ Alr,
    const u16* __restrict__ df_,   const u16* __restrict__ dr_,
    const float* __restrict__ Dskf, const float* __restrict__ Dskr,
    const float* __restrict__ hin,
    u16* __restrict__ yf, const u16* __restrict__ szp)
{
  const int e = blockIdx.x * 128 + threadIdx.x;
  const int c = blockIdx.y;
  const int b = blockIdx.z;
  const float* bc = DIR ? bcr : bcf;
  const u16* x    = DIR ? xr_ : xf_;
  const float* Al = DIR ? Alr : Alf;
  const u16* dpre = DIR ? dr_ : df_;
  const float dskip = (DIR ? Dskr : Dskf)[e];

  float A20;
  const bool structured = a_check(Al, e, A20);

  const int g = (DIR * 2 + b) * DI + e;
  const size_t cb = (size_t)c * NCHAN + (size_t)g * DS;
  const size_t m0 = (size_t)b * SEQ + (size_t)c * CT_;

  auto emit = [&](size_t m, int t_abs, float yout) {
    if (DIR == 0) {
      yf[m * DI + e] = f2bf(yout);
    } else {
      const size_t moi = ((size_t)b * SEQ + (SEQ - 1 - t_abs)) * DI + e;
      yf[moi] = f2bf((bf2f(yf[moi]) + yout) * bf2f(szp[moi]));
    }
  };

  if (structured) {
    f32x2 h2[8];
    #pragma unroll
    for (int k = 0; k < 8; k++) h2[k] = *(const f32x2*)&hin[cb + 2 * k];
    #pragma unroll 2
    for (int t = 0; t < CT_; t++) {
      const size_t m = m0 + t;
      const float d  = bf2f(dpre[m * DI + e]);
      const float xv = bf2f(x[m * DI + e]);
      const float dbx = d * xv;
      const f32x4* bp = (const f32x4*)(bc + m * 32);
      const f32x4 b0 = bp[0], b1 = bp[1], b2 = bp[2], b3 = bp[3];
      const f32x4 c0 = bp[4], c1 = bp[5], c2 = bp[6], c3 = bp[7];
      const float q = fexp2(A20 * d), q2 = q * q, q4 = q2 * q2, q8 = q4 * q4;
      const f32x2 q2v = (f32x2){q2, q2}, q4v = (f32x2){q4, q4}, q8v = (f32x2){q8, q8};
      const f32x2 dbx2 = (f32x2){dbx, dbx};
      const f32x2 p0 = (f32x2){q, q2};
      const f32x2 p1 = p0 * q2v, p2 = p0 * q4v, p3 = p1 * q4v;
      const f32x2 p4 = p0 * q8v, p5 = p1 * q8v, p6 = p2 * q8v, p7 = p3 * q8v;
      f32x2 y2 = (f32x2){0.f, 0.f};
      h2[0] = p0 * h2[0] + dbx2 * (f32x2){b0[0], b0[1]};  y2 = y2 + h2[0] * (f32x2){c0[0], c0[1]};
      h2[1] = p1 * h2[1] + dbx2 * (f32x2){b0[2], b0[3]};  y2 = y2 + h2[1] * (f32x2){c0[2], c0[3]};
      h2[2] = p2 * h2[2] + dbx2 * (f32x2){b1[0], b1[1]};  y2 = y2 + h2[2] * (f32x2){c1[0], c1[1]};
      h2[3] = p3 * h2[3] + dbx2 * (f32x2){b1[2], b1[3]};  y2 = y2 + h2[3] * (f32x2){c1[2], c1[3]};
      h2[4] = p4 * h2[4] + dbx2 * (f32x2){b2[0], b2[1]};  y2 = y2 + h2[4] * (f32x2){c2[0], c2[1]};
      h2[5] = p5 * h2[5] + dbx2 * (f32x2){b2[2], b2[3]};  y2 = y2 + h2[5] * (f32x2){c2[2], c2[3]};
      h2[6] = p6 * h2[6] + dbx2 * (f32x2){b3[0], b3[1]};  y2 = y2 + h2[6] * (f32x2){c3[0], c3[1]};
      h2[7] = p7 * h2[7] + dbx2 * (f32x2){b3[2], b3[3]};  y2 = y2 + h2[7] * (f32x2){c3[2], c3[3]};
      emit(m, c * CT_ + t, (y2[0] + y2[1]) + xv * dskip);
    }
  } else {
    float A2[DS], h[DS];
    #pragma unroll
    for (int n = 0; n < DS; n++) A2[n] = -__expf(Al[e * DS + n]) * LOG2E;
    #pragma unroll
    for (int n = 0; n < DS; n++) h[n] = hin[cb + n];
    for (int t = 0; t < CT_; t++) {
      const size_t m = m0 + t;
      const float d  = bf2f(dpre[m * DI + e]);
      const float xv = bf2f(x[m * DI + e]);
      const float dbx = d * xv;
      float dAv[DS];
      dA_generic(d, A2, dAv);
      float y = 0.f;
      #pragma unroll
      for (int n = 0; n < DS; n++) {
        h[n] = dAv[n] * h[n] + dbx * bc[m * 32 + n];
        y += h[n] * bc[m * 32 + 16 + n];
      }
      emit(m, c * CT_ + t, y + xv * dskip);
    }
  }
}

// ---------------------------------------------------------------------------
// Legacy (low-ws) scan kernels: bf16 xdbl operands, on-the-fly delta.
// ---------------------------------------------------------------------------
__global__ __launch_bounds__(256) void scanA_k(
    const u16* __restrict__ xdblf_, const u16* __restrict__ xdblr_,
    const u16* __restrict__ xf_,    const u16* __restrict__ xr_,
    const float* __restrict__ Alf,  const float* __restrict__ Alr,
    const float* __restrict__ dtwf, const float* __restrict__ dtwr,
    const float* __restrict__ dtbf, const float* __restrict__ dtbr,
    float* __restrict__ sumdP, float* __restrict__ bP, int ct)
{
  const int e = blockIdx.x * 256 + threadIdx.x;
  const int c = blockIdx.y;
  const int dir = blockIdx.z >> 1, b = blockIdx.z & 1;
  const u16* xdbl = dir ? xdblr_ : xdblf_;
  const u16* x    = dir ? xr_ : xf_;
  const float* Al = dir ? Alr : Alf;

  float A2[DS], h[DS], dw[DTR];
  #pragma unroll
  for (int n = 0; n < DS; n++) { A2[n] = -__expf(Al[e * DS + n]) * LOG2E; h[n] = 0.f; }
  const float* dtw = dir ? dtwr : dtwf;
  #pragma unroll
  for (int r = 0; r < DTR; r += 4) {
    const float4 v = *(const float4*)(dtw + e * DTR + r);
    dw[r] = v.x; dw[r+1] = v.y; dw[r+2] = v.z; dw[r+3] = v.w;
  }
  const float bias = (dir ? dtbr : dtbf)[e];

  float sumd = 0.f;
  const size_t m0 = (size_t)b * SEQ + (size_t)c * ct;
  for (int t = 0; t < ct; t++) {
    const size_t m = m0 + t;
    union { uint4 v[4]; u16 s[32]; } DT;
    #pragma unroll
    for (int q = 0; q < 4; q++) DT.v[q] = ((const uint4*)(xdbl + m * 64))[q];
    float a0 = 0.f, a1 = 0.f, a2 = 0.f, a3 = 0.f;
    #pragma unroll
    for (int r = 0; r < DTR; r += 4) {
      a0 += bf2f(DT.s[r+0]) * dw[r+0];
      a1 += bf2f(DT.s[r+1]) * dw[r+1];
      a2 += bf2f(DT.s[r+2]) * dw[r+2];
      a3 += bf2f(DT.s[r+3]) * dw[r+3];
    }
    const float d = softplus_f(((a0 + a1) + (a2 + a3)) + bias);
    const float xv  = bf2f(x[m * DI + e]);
    const float dbx = d * xv;
    sumd += d;
    union { uint4 v[2]; u16 s[16]; } Bv;
    Bv.v[0] = ((const uint4*)(xdbl + m * 64 + 32))[0];
    Bv.v[1] = ((const uint4*)(xdbl + m * 64 + 32))[1];
    float dAv[DS];
    dA_generic(d, A2, dAv);
    #pragma unroll
    for (int n = 0; n < DS; n++)
      h[n] = dAv[n] * h[n] + dbx * bf2f(Bv.s[n]);
  }
  const int g = (dir * 2 + b) * DI + e;
  const size_t cb = (size_t)c * NCHAN + (size_t)g * DS;
  #pragma unroll
  for (int n = 0; n < DS; n++) bP[cb + n] = h[n];
  sumdP[(size_t)c * NG + g] = sumd;
}

template<int MODE>
__global__ __launch_bounds__(256) void scanC_k(
    const u16* __restrict__ xdblf_, const u16* __restrict__ xdblr_,
    const u16* __restrict__ xf_,    const u16* __restrict__ xr_,
    const float* __restrict__ Alf,  const float* __restrict__ Alr,
    const float* __restrict__ dtwf, const float* __restrict__ dtwr,
    const float* __restrict__ dtbf, const float* __restrict__ dtbr,
    const float* __restrict__ Dskf, const float* __restrict__ Dskr,
    const float* __restrict__ hin,
    u16* __restrict__ yf, u16* __restrict__ yr,
    const u16* __restrict__ szp, int ct)
{
  const int e = blockIdx.x * 256 + threadIdx.x;
  const int c = blockIdx.y;
  const int dir = (MODE == 2); const int b = blockIdx.z;
  const u16* xdbl = dir ? xdblr_ : xdblf_;
  const u16* x    = dir ? xr_ : xf_;
  const float* Al = dir ? Alr : Alf;
  const float dskip = (dir ? Dskr : Dskf)[e];

  float A2[DS], h[DS], dw[DTR];
  #pragma unroll
  for (int n = 0; n < DS; n++) A2[n] = -__expf(Al[e * DS + n]) * LOG2E;
  const float* dtw = dir ? dtwr : dtwf;
  #pragma unroll
  for (int r = 0; r < DTR; r += 4) {
    const float4 v = *(const float4*)(dtw + e * DTR + r);
    dw[r] = v.x; dw[r+1] = v.y; dw[r+2] = v.z; dw[r+3] = v.w;
  }
  const float bias = (dir ? dtbr : dtbf)[e];

  const int g = (dir * 2 + b) * DI + e;
  const size_t cb = (size_t)c * NCHAN + (size_t)g * DS;
  #pragma unroll
  for (int n = 0; n < DS; n++) h[n] = hin[cb + n];
  const size_t m0 = (size_t)b * SEQ + (size_t)c * ct;

  for (int t = 0; t < ct; t++) {
    const size_t m = m0 + t;
    union { uint4 v[4]; u16 s[32]; } BC;
    #pragma unroll
    for (int q = 0; q < 4; q++) BC.v[q] = ((const uint4*)(xdbl + m * 64 + 32))[q];
    union { uint4 v[4]; u16 s[32]; } DT;
    #pragma unroll
    for (int q = 0; q < 4; q++) DT.v[q] = ((const uint4*)(xdbl + m * 64))[q];
    float a0 = 0.f, a1 = 0.f, a2 = 0.f, a3 = 0.f;
    #pragma unroll
    for (int r = 0; r < DTR; r += 4) {
      a0 += bf2f(DT.s[r+0]) * dw[r+0];
      a1 += bf2f(DT.s[r+1]) * dw[r+1];
      a2 += bf2f(DT.s[r+2]) * dw[r+2];
      a3 += bf2f(DT.s[r+3]) * dw[r+3];
    }
    const float d = softplus_f(((a0 + a1) + (a2 + a3)) + bias);
    const float xv  = bf2f(x[m * DI + e]);
    const float dbx = d * xv;
    float dAv[DS];
    dA_generic(d, A2, dAv);
    float y = 0.f;
    #pragma unroll
    for (int n = 0; n < DS; n++) {
      h[n] = dAv[n] * h[n] + dbx * bf2f(BC.s[n]);
      y += h[n] * bf2f(BC.s[16 + n]);
    }
    const float yout = y + xv * dskip;
    if (MODE == 1) {
      yf[m * DI + e] = f2bf(yout);
    } else {
      const size_t mo = (size_t)b * SEQ + (SEQ - 1 - (c * ct + t));
      const size_t moi = mo * DI + e;
      yr[moi] = f2bf((bf2f(yf[moi]) + yout) * bf2f(szp[moi]));
    }
  }
}

// ---------------------------------------------------------------------------
extern "C" void kernel_launch(void* const* d_in, const int* in_sizes, int n_in,
                              void* d_out, int out_size, void* d_ws, size_t ws_size,
                              hipStream_t stream)
{
  (void)in_sizes; (void)n_in; (void)out_size;
  const float* u      = (const float*)d_in[0];
  const float* in_w   = (const float*)d_in[1];
  const float* out_w  = (const float*)d_in[2];
  const float* cw_f   = (const float*)d_in[3];
  const float* cb_f   = (const float*)d_in[4];
  const float* xw_f   = (const float*)d_in[5];
  const float* dtw_f  = (const float*)d_in[6];
  const float* dtb_f  = (const float*)d_in[7];
  const float* Alog_f = (const float*)d_in[8];
  const float* D_f    = (const float*)d_in[9];
  const float* cw_r   = (const float*)d_in[10];
  const float* cb_r   = (const float*)d_in[11];
  const float* xw_r   = (const float*)d_in[12];
  const float* dtw_r  = (const float*)d_in[13];
  const float* dtb_r  = (const float*)d_in[14];
  const float* Alog_r = (const float*)d_in[15];
  const float* D_r    = (const float*)d_in[16];

  const size_t mexe = (size_t)M_TOT * DI;          // 16.78M elements
  const size_t bc_bytes = (size_t)M_TOT * 32 * 4;  // 2.1 MB f32 BC per dir
  const size_t need_big =
      5 * (mexe * 2) + 2 * ((size_t)M_TOT * 64 * 2) + 2 * bc_bytes +
      (size_t)WU_TOT * 16 +
      (size_t)128 * NG * 4 + (size_t)128 * NCHAN * 4 + 64 * 256;
  const bool big = (ws_size >= need_big);
  const int nchunk = big ? 128 : 64;
  const int ct = SEQ / nchunk;

  char* ws = (char*)d_ws;
  size_t off = 0;
  auto alloc = [&](size_t bytes) -> void* {
    void* p = ws + off;
    off += (bytes + 255) & ~(size_t)255;
    return p;
  };
  u16*   ubf   = (u16*)alloc(mexe * 2);            // bf16 u; dead after in_proj -> df
  u16*   xpre  = (u16*)alloc(mexe * 2);            // dead after conv -> yr (legacy)
  u16*   xf    = (u16*)alloc(mexe * 2);            // x_f; in-place y_f / combined y
  u16*   xr    = (u16*)alloc(mexe * 2);
  u16*   xdblf = (u16*)alloc((size_t)M_TOT * 64 * 2);
  u16*   xdblr = (u16*)alloc((size_t)M_TOT * 64 * 2);
  float* bc32f = (float*)alloc(bc_bytes);          // f32 B/C operand, dir f
  float* bc32r = (float*)alloc(bc_bytes);
  u16*   wbf   = (u16*)alloc((size_t)WU_TOT * 16); // bf16 weight arena
  float* sumdP = (float*)alloc((size_t)nchunk * NG * 4);
  float* bP    = (float*)alloc((size_t)nchunk * NCHAN * 4);
  u16*   dr    = big ? (u16*)alloc(mexe * 2) : nullptr;
  u16*   df    = ubf;                              // alias (u dead after in_proj)
  u16*   szb   = (u16*)d_out;                      // silu(z) in d_out (dead before out_proj)

  // weight arena sub-pointers (units of 8 elems = 16 B)
  u16* winb  = wbf;
  u16* xwbf  = wbf + (size_t)WU_INW * 8;
  u16* xwbr  = xwbf + (size_t)WU_XW * 8;
  u16* dtwbf = xwbr + (size_t)WU_XW * 8;
  u16* dtwbr = dtwbf + (size_t)WU_DTW * 8;
  u16* outwb = dtwbr + (size_t)WU_DTW * 8;

  dim3 blk(256);
  // 0) convert u + weights to bf16.  u has M_TOT*DM = 8.39M elems -> 4096 blocks.
  cvt_k<<<dim3((unsigned)((size_t)M_TOT * DM / 8 / 256)), blk, 0, stream>>>(u, ubf);
  cvtw_k<<<dim3(WU_TOT / 256), blk, 0, stream>>>(in_w, xw_f, xw_r, dtw_f, dtw_r, out_w, wbf);
  // 1) in_proj (BK=64)
  gemm_k<128, 64, 0, false><<<dim3(128, 16), blk, 0, stream>>>(
      ubf, nullptr, DM, winb, nullptr, DM, xpre, nullptr, szb, nullptr, nullptr, nullptr, 0);
  // 2) depthwise conv + silu, both dirs in one pass
  conv2_k<<<dim3(SEQ / (2 * CLT), B_SZ), blk, 0, stream>>>(
      xpre, cw_f, cb_f, cw_r, cb_r, xf, xr);
  // 3) xproj (dual, BK=64): xdbl = x @ xproj_w^T ; n>=32 also stored f32 to bc32
  gemm_k<64, 64, 1, true><<<dim3(128, 1, 2), blk, 0, stream>>>(
      xf, xr, DI, xwbf, xwbr, DI, xdblf, xdblr, bc32f, bc32r, nullptr, nullptr, 64);

  if (big) {
    // 4) delta (dual, BK=32 since K=32)
    gemm_k<128, 32, 2, true><<<dim3(128, 8, 2), blk, 0, stream>>>(
        xdblf, xdblr, 64, dtwbf, dtwbr, DTR, df, dr, nullptr, nullptr, dtb_f, dtb_r, DI);
    // 5) scan
    scanA2_k<64><<<dim3(8, nchunk, 4), dim3(128), 0, stream>>>(
        bc32f, bc32r, xf, xr, Alog_f, Alog_r, df, dr, sumdP, bP);
    scanB_k<<<dim3(NCHAN / 256), blk, 0, stream>>>(sumdP, bP, Alog_f, Alog_r, nchunk);
    // dir0 then dir1 (dir1 fuses the (yf+yr)*sz combine; sequential => no race)
    scanC2_k<64, 0><<<dim3(8, nchunk, 2), dim3(128), 0, stream>>>(
        bc32f, bc32r, xf, xr, Alog_f, Alog_r, df, dr, D_f, D_r, bP, xf, szb);
    scanC2_k<64, 1><<<dim3(8, nchunk, 2), dim3(128), 0, stream>>>(
        bc32f, bc32r, xf, xr, Alog_f, Alog_r, df, dr, D_f, D_r, bP, xf, szb);
    // 6) out_proj (BK=64) from combined xf
    gemm_k<128, 64, 3, false><<<dim3(128, 4), blk, 0, stream>>>(
        xf, nullptr, DI, outwb, nullptr, DI, d_out, nullptr, nullptr, nullptr, nullptr, nullptr, DM);
  } else {
    // legacy (low-ws) path
    scanA_k<<<dim3(4, nchunk, 4), blk, 0, stream>>>(
        xdblf, xdblr, xf, xr, Alog_f, Alog_r, dtw_f, dtw_r, dtb_f, dtb_r,
        sumdP, bP, ct);
    scanB_k<<<dim3(NCHAN / 256), blk, 0, stream>>>(sumdP, bP, Alog_f, Alog_r, nchunk);
    scanC_k<1><<<dim3(4, nchunk, 2), blk, 0, stream>>>(
        xdblf, xdblr, xf, xr, Alog_f, Alog_r, dtw_f, dtw_r, dtb_f, dtb_r,
        D_f, D_r, bP, xf, nullptr, nullptr, ct);
    scanC_k<2><<<dim3(4, nchunk, 2), blk, 0, stream>>>(
        xdblf, xdblr, xf, xr, Alog_f, Alog_r, dtw_f, dtw_r, dtb_f, dtb_r,
        D_f, D_r, bP, xf, xpre, szb, ct);
    gemm_k<128, 64, 3, false><<<dim3(128, 4), blk, 0, stream>>>(
        xpre, nullptr, DI, outwb, nullptr, DI, d_out, nullptr, nullptr, nullptr, nullptr, nullptr, DM);
  }
}

// Round 17
// 353.657 us; speedup vs baseline: 1.0615x; 1.0615x over previous
//
#include <hip/hip_runtime.h>
#include <hip/hip_bf16.h>
#include <math.h>

#define B_SZ 2
#define SEQ  8192
#define DM   512
#define DI   1024
#define DS   16
#define DTR  32
#define M_TOT (B_SZ*SEQ)        // 16384 positions
#define LOG2E 1.44269504088896f
#define NCHAN  (4*DI*DS)        // 65536 scan channels ((dir*2+b)*DI+e)*DS+n
#define NG     (4*DI)           // 4096 (dir,b,e) groups
#define CLT    8                // conv timesteps per thread

typedef __attribute__((ext_vector_type(8))) short bf16x8;
typedef __attribute__((ext_vector_type(4))) float f32x4;
typedef __attribute__((ext_vector_type(2))) float f32x2;
typedef unsigned short u16;

__device__ __forceinline__ float bf2f(u16 u){
  union { unsigned u; float f; } v; v.u = ((unsigned)u) << 16; return v.f;
}
__device__ __forceinline__ u16 f2bf(float f){
  union { float f; unsigned u; } v; v.f = f;
  unsigned r = v.u + 0x7FFFu + ((v.u >> 16) & 1u);
  return (u16)(r >> 16);
}
__device__ __forceinline__ float silu_f(float x){ return x / (1.f + __expf(-x)); }
__device__ __forceinline__ float softplus_f(float x){
  return (x > 15.f) ? x : __logf(1.f + __expf(x));
}
__device__ __forceinline__ float fexp2(float x){ return __builtin_amdgcn_exp2f(x); }

__device__ __forceinline__ void dA_generic(float d, const float* A2, float* dAv){
  #pragma unroll
  for (int n = 0; n < DS; n++) dAv[n] = fexp2(A2[n] * d);
}

// ---------------------------------------------------------------------------
// f32 -> bf16 bulk convert, 8 elems/thread.
// ---------------------------------------------------------------------------
__global__ __launch_bounds__(256) void cvt_k(
    const float* __restrict__ s, u16* __restrict__ d)
{
  const size_t i = (size_t)blockIdx.x * 256 + threadIdx.x;
  const float4 a = ((const float4*)s)[i * 2];
  const float4 b = ((const float4*)s)[i * 2 + 1];
  union { uint4 v; u16 h[8]; } o;
  o.h[0] = f2bf(a.x); o.h[1] = f2bf(a.y); o.h[2] = f2bf(a.z); o.h[3] = f2bf(a.w);
  o.h[4] = f2bf(b.x); o.h[5] = f2bf(b.y); o.h[6] = f2bf(b.z); o.h[7] = f2bf(b.w);
  ((uint4*)d)[i] = o.v;
}

// Packed weight convert: 6 tensors -> one bf16 arena. Unit = 8 elems.
#define WU_INW  131072
#define WU_XW   8192
#define WU_DTW  4096
#define WU_OUTW 65536
#define WU_TOT  (WU_INW + 2*WU_XW + 2*WU_DTW + WU_OUTW)   // 221184
__global__ __launch_bounds__(256) void cvtw_k(
    const float* __restrict__ inw, const float* __restrict__ xwf,
    const float* __restrict__ xwr, const float* __restrict__ dtwf,
    const float* __restrict__ dtwr, const float* __restrict__ outw,
    u16* __restrict__ dst)
{
  int i = blockIdx.x * 256 + threadIdx.x;
  const float* s;
  int base = 0;
  if (i < WU_INW) { s = inw; }
  else if ((i -= WU_INW) < WU_XW) { s = xwf; base = WU_INW; }
  else if ((i -= WU_XW) < WU_XW)  { s = xwr; base = WU_INW + WU_XW; }
  else if ((i -= WU_XW) < WU_DTW) { s = dtwf; base = WU_INW + 2*WU_XW; }
  else if ((i -= WU_DTW) < WU_DTW){ s = dtwr; base = WU_INW + 2*WU_XW + WU_DTW; }
  else { i -= WU_DTW; s = outw; base = WU_INW + 2*WU_XW + 2*WU_DTW; }
  const float4 a = ((const float4*)s)[i * 2];
  const float4 b = ((const float4*)s)[i * 2 + 1];
  union { uint4 v; u16 h[8]; } o;
  o.h[0] = f2bf(a.x); o.h[1] = f2bf(a.y); o.h[2] = f2bf(a.z); o.h[3] = f2bf(a.w);
  o.h[4] = f2bf(b.x); o.h[5] = f2bf(b.y); o.h[6] = f2bf(b.z); o.h[7] = f2bf(b.w);
  ((uint4*)(dst))[base + i] = o.v;
}

// ---------------------------------------------------------------------------
// MFMA bf16 GEMM, global_load_lds staging + XOR swizzle, templated BK.
// EPI: 0 = split xz; 1 = bf16 + f32 side-store n>=32; 2 = softplus+bias; 3 = f32
// ---------------------------------------------------------------------------
template<int BN, int BK, int EPI, bool DUAL>
__global__ __launch_bounds__(256) void gemm_k(
    const u16* __restrict__ Ap,  const u16* __restrict__ Ap2, int lda,
    const u16* __restrict__ Bw,  const u16* __restrict__ Bw2, int K,
    void* __restrict__ out0, void* __restrict__ out02,
    void* __restrict__ out1, void* __restrict__ out12,
    const float* __restrict__ bias, const float* __restrict__ bias2, int ldo)
{
  constexpr int BM = 128;
  constexpr int NSLOT = BK / 8;        // 16B slots per LDS row
  constexpr int RPI   = 512 / BK;      // rows covered by one 1KB wave-issue
  __shared__ __align__(16) u16 As[BM * BK];
  __shared__ __align__(16) u16 Bs[BN * BK];
  const int tid  = threadIdx.x;
  const int lane = tid & 63, wid = tid >> 6;
  const int mt = blockIdx.x, nt = blockIdx.y;
  const int z  = DUAL ? blockIdx.z : 0;
  const u16* A = z ? Ap2 : Ap;
  const u16* W = z ? Bw2 : Bw;
  void* o0 = z ? out02 : out0;
  void* o1 = z ? out12 : out1;
  const float* bi = z ? bias2 : bias;

  constexpr int FM = (BN == 128) ? 4 : 2;
  const int wm = (BN == 128) ? ((wid >> 1) * 64) : (wid * 32);
  const int wn = (BN == 128) ? ((wid & 1) * 64) : 0;

  f32x4 acc[FM][4];
  #pragma unroll
  for (int i = 0; i < FM; i++)
    #pragma unroll
    for (int j = 0; j < 4; j++)
      acc[i][j] = (f32x4){0.f, 0.f, 0.f, 0.f};

  const int sr   = lane / NSLOT;                 // row within RPI-row chunk
  const int slot = lane % NSLOT;
  const int skey = (BK == 32) ? ((sr >> 1) & 3) : (sr & 7);
  const int sc   = (slot ^ skey) * 8;            // pre-swizzled source col

  for (int k0 = 0; k0 < K; k0 += BK) {
    #pragma unroll
    for (int j = 0; j < BM / RPI / 4; j++) {     // A issues per wave
      const int chunk = wid * (BM / RPI / 4) + j;
      const u16* src = A + (size_t)(mt * BM + chunk * RPI + sr) * lda + (k0 + sc);
      __builtin_amdgcn_global_load_lds(
          (const __attribute__((address_space(1))) void*)src,
          (__attribute__((address_space(3))) void*)(As + chunk * 512), 16, 0, 0);
    }
    #pragma unroll
    for (int j = 0; j < BN / RPI / 4; j++) {     // B issues per wave
      const int chunk = wid * (BN / RPI / 4) + j;
      const u16* src = W + (size_t)(nt * BN + chunk * RPI + sr) * K + (k0 + sc);
      __builtin_amdgcn_global_load_lds(
          (const __attribute__((address_space(1))) void*)src,
          (__attribute__((address_space(3))) void*)(Bs + chunk * 512), 16, 0, 0);
    }
    __syncthreads();

    const int row  = lane & 15;
    const int rkey = (BK == 32) ? ((row >> 1) & 3) : (row & 7);
    #pragma unroll
    for (int kh = 0; kh < BK / 32; kh++) {
      const int sl = (kh * 4 + (lane >> 4)) ^ rkey;   // swizzled 16B slot
      bf16x8 af[FM], bfr[4];
      #pragma unroll
      for (int i = 0; i < FM; i++)
        af[i] = *(const bf16x8*)&As[(wm + i * 16 + row) * BK + sl * 8];
      #pragma unroll
      for (int j = 0; j < 4; j++)
        bfr[j] = *(const bf16x8*)&Bs[(wn + j * 16 + row) * BK + sl * 8];
      #pragma unroll
      for (int i = 0; i < FM; i++)
        #pragma unroll
        for (int j = 0; j < 4; j++)
          acc[i][j] = __builtin_amdgcn_mfma_f32_16x16x32_bf16(af[i], bfr[j], acc[i][j], 0, 0, 0);
    }
    __syncthreads();
  }

  const int rb4 = (lane >> 4) * 4, col = lane & 15;
  #pragma unroll
  for (int i = 0; i < FM; i++) {
    #pragma unroll
    for (int j = 0; j < 4; j++) {
      #pragma unroll
      for (int r = 0; r < 4; r++) {
        const int m = mt * BM + wm + i * 16 + rb4 + r;
        const int n = nt * BN + wn + j * 16 + col;
        const float v = acc[i][j][r];
        if (EPI == 0) {
          if (n < DI) ((u16*)o0)[(size_t)m * DI + n] = f2bf(v);
          else        ((u16*)out1)[(size_t)m * DI + (n - DI)] = f2bf(silu_f(v));
        } else if (EPI == 1) {
          ((u16*)o0)[(size_t)m * ldo + n] = f2bf(v);
          if (n >= 32) ((float*)o1)[(size_t)m * 32 + (n - 32)] = v;
        } else if (EPI == 2) {
          ((u16*)o0)[(size_t)m * ldo + n] = f2bf(softplus_f(v + bi[n]));
        } else {
          ((float*)o0)[(size_t)m * ldo + n] = v;
        }
      }
    }
  }
}

// ---------------------------------------------------------------------------
// Depthwise causal conv(4) + bias + silu, BOTH directions in one ascending pass.
// ---------------------------------------------------------------------------
__global__ __launch_bounds__(256) void conv2_k(
    const u16* __restrict__ xpre,
    const float* __restrict__ wf, const float* __restrict__ bf_,
    const float* __restrict__ wr, const float* __restrict__ br_,
    u16* __restrict__ xf, u16* __restrict__ xr)
{
  const int tid  = threadIdx.x;
  const int et   = tid & 127;
  const int lsub = tid >> 7;
  const int e0 = et * 8;
  const int b  = blockIdx.y;
  const int l0 = (blockIdx.x * 2 + lsub) * CLT;
  const size_t base = (size_t)b * SEQ * DI + e0;

  float4 wf4[8], wr4[8];
  float  bfv[8], brv[8];
  #pragma unroll
  for (int j = 0; j < 8; j++) {
    wf4[j] = *(const float4*)(wf + (e0 + j) * 4);
    wr4[j] = *(const float4*)(wr + (e0 + j) * 4);
    bfv[j] = bf_[e0 + j];
    brv[j] = br_[e0 + j];
  }

  float c0[8], c1[8], c2[8];
  auto loadv = [&](int l, float* dst) {
    if (l < 0 || l >= SEQ) {
      #pragma unroll
      for (int j = 0; j < 8; j++) dst[j] = 0.f;
      return;
    }
    union { uint4 v; u16 s[8]; } t;
    t.v = *(const uint4*)(xpre + base + (size_t)l * DI);
    #pragma unroll
    for (int j = 0; j < 8; j++) dst[j] = bf2f(t.s[j]);
  };
  loadv(l0 - 3, c0); loadv(l0 - 2, c1); loadv(l0 - 1, c2);

  #pragma unroll
  for (int i = 0; i < CLT + 3; i++) {
    const int l = l0 + i;
    float cn[8];
    loadv(l, cn);
    if (i < CLT) {
      union { uint4 v; u16 s[8]; } o;
      #pragma unroll
      for (int j = 0; j < 8; j++) {
        const float v = bfv[j] + wf4[j].x * c0[j] + wf4[j].y * c1[j]
                               + wf4[j].z * c2[j] + wf4[j].w * cn[j];
        o.s[j] = f2bf(silu_f(v));
      }
      *(uint4*)(xf + base + (size_t)l * DI) = o.v;
    }
    if (i >= 3) {
      const int lr = l - 3;
      union { uint4 v; u16 s[8]; } o;
      #pragma unroll
      for (int j = 0; j < 8; j++) {
        const float v = brv[j] + wr4[j].w * c0[j] + wr4[j].z * c1[j]
                               + wr4[j].y * c2[j] + wr4[j].x * cn[j];
        o.s[j] = f2bf(silu_f(v));
      }
      *(uint4*)(xr + base + (size_t)(SEQ - 1 - lr) * DI) = o.v;
    }
    #pragma unroll
    for (int j = 0; j < 8; j++) { c0[j] = c1[j]; c1[j] = c2[j]; c2[j] = cn[j]; }
  }
}

// structured-A check + A20 for channel e
__device__ __forceinline__ bool a_check(const float* Al, int e, float& A20){
  float A2[DS];
  #pragma unroll
  for (int n = 0; n < DS; n++) A2[n] = -__expf(Al[e * DS + n]) * LOG2E;
  A20 = A2[0];
  bool st = true;
  #pragma unroll
  for (int n = 1; n < DS; n++)
    st = st && (fabsf(A2[n] - (float)(n + 1) * A20) <= 1e-3f * fabsf(A2[n]));
  return st;
}

// ---------------------------------------------------------------------------
// Big-path scan pass A: 1 channel/thread, f32 BC uniform loads, CT compile-time.
// grid: (8, nchunk, 4=dir*2+b), 128 thr
// ---------------------------------------------------------------------------
template<int CT_>
__global__ __launch_bounds__(128) void scanA2_k(
    const float* __restrict__ bcf, const float* __restrict__ bcr,
    const u16* __restrict__ xf_,   const u16* __restrict__ xr_,
    const float* __restrict__ Alf, const float* __restrict__ Alr,
    const u16* __restrict__ df_,   const u16* __restrict__ dr_,
    float* __restrict__ sumdP, float* __restrict__ bP)
{
  const int e = blockIdx.x * 128 + threadIdx.x;
  const int c = blockIdx.y;
  const int dir = blockIdx.z >> 1, b = blockIdx.z & 1;
  const float* bc = dir ? bcr : bcf;
  const u16* x    = dir ? xr_ : xf_;
  const float* Al = dir ? Alr : Alf;
  const u16* dpre = dir ? dr_ : df_;

  float A20;
  const bool structured = a_check(Al, e, A20);

  float sumd = 0.f;
  const size_t m0 = (size_t)b * SEQ + (size_t)c * CT_;
  const int g = (dir * 2 + b) * DI + e;
  const size_t cb = (size_t)c * NCHAN + (size_t)g * DS;

  if (structured) {
    f32x2 h2[8];
    #pragma unroll
    for (int k = 0; k < 8; k++) h2[k] = (f32x2){0.f, 0.f};
    #pragma unroll 2
    for (int t = 0; t < CT_; t++) {
      const size_t m = m0 + t;
      const float d  = bf2f(dpre[m * DI + e]);
      const float xv = bf2f(x[m * DI + e]);
      const float dbx = d * xv;
      sumd += d;
      const f32x4* bp = (const f32x4*)(bc + m * 32);
      const f32x4 b0 = bp[0], b1 = bp[1], b2 = bp[2], b3 = bp[3];
      const float q = fexp2(A20 * d), q2 = q * q, q4 = q2 * q2, q8 = q4 * q4;
      const f32x2 q2v = (f32x2){q2, q2}, q4v = (f32x2){q4, q4}, q8v = (f32x2){q8, q8};
      const f32x2 dbx2 = (f32x2){dbx, dbx};
      const f32x2 p0 = (f32x2){q, q2};
      const f32x2 p1 = p0 * q2v, p2 = p0 * q4v, p3 = p1 * q4v;
      const f32x2 p4 = p0 * q8v, p5 = p1 * q8v, p6 = p2 * q8v, p7 = p3 * q8v;
      h2[0] = p0 * h2[0] + dbx2 * (f32x2){b0[0], b0[1]};
      h2[1] = p1 * h2[1] + dbx2 * (f32x2){b0[2], b0[3]};
      h2[2] = p2 * h2[2] + dbx2 * (f32x2){b1[0], b1[1]};
      h2[3] = p3 * h2[3] + dbx2 * (f32x2){b1[2], b1[3]};
      h2[4] = p4 * h2[4] + dbx2 * (f32x2){b2[0], b2[1]};
      h2[5] = p5 * h2[5] + dbx2 * (f32x2){b2[2], b2[3]};
      h2[6] = p6 * h2[6] + dbx2 * (f32x2){b3[0], b3[1]};
      h2[7] = p7 * h2[7] + dbx2 * (f32x2){b3[2], b3[3]};
    }
    #pragma unroll
    for (int k = 0; k < 8; k++) *(f32x2*)&bP[cb + 2 * k] = h2[k];
  } else {
    float A2[DS], h[DS];
    #pragma unroll
    for (int n = 0; n < DS; n++) { A2[n] = -__expf(Al[e * DS + n]) * LOG2E; h[n] = 0.f; }
    for (int t = 0; t < CT_; t++) {
      const size_t m = m0 + t;
      const float d  = bf2f(dpre[m * DI + e]);
      const float xv = bf2f(x[m * DI + e]);
      const float dbx = d * xv;
      sumd += d;
      float dAv[DS];
      dA_generic(d, A2, dAv);
      #pragma unroll
      for (int n = 0; n < DS; n++)
        h[n] = dAv[n] * h[n] + dbx * bc[m * 32 + n];
    }
    #pragma unroll
    for (int n = 0; n < DS; n++) bP[cb + n] = h[n];
  }
  sumdP[(size_t)c * NG + g] = sumd;
}

// Scan pass B: cross-chunk scan, in place (bP becomes h_in per chunk).
__global__ __launch_bounds__(256) void scanB_k(
    const float* __restrict__ sumdP, float* __restrict__ bP,
    const float* __restrict__ Alog_f, const float* __restrict__ Alog_r, int nchunk)
{
  const int ch = blockIdx.x * 256 + threadIdx.x;   // 0..65535
  const int g = ch >> 4, n = ch & 15;
  const int dir = g >> 11, e = g & (DI - 1);
  const float* Al = dir ? Alog_r : Alog_f;
  const float A2 = -__expf(Al[e * DS + n]) * LOG2E;
  float h = 0.f;
  for (int c = 0; c < nchunk; c++) {
    const float a = fexp2(A2 * sumdP[(size_t)c * NG + g]);
    const size_t i = (size_t)c * NCHAN + ch;
    const float bb = bP[i];
    bP[i] = h;              // h_in for chunk c
    h = a * h + bb;
  }
}

// ---------------------------------------------------------------------------
// Big-path scan pass C (merged dirs): emit y (+ x*D). CT compile-time.
// dir0 -> yf[m] (in place over x_f); dir1 -> yr[mo] (mo = flipped).
// grid: (8, nchunk, 4), 128 thr
// ---------------------------------------------------------------------------
template<int CT_>
__global__ __launch_bounds__(128) void scanC2_k(
    const float* __restrict__ bcf, const float* __restrict__ bcr,
    const u16* __restrict__ xf_,   const u16* __restrict__ xr_,
    const float* __restrict__ Alf, const float* __restrict__ Alr,
    const u16* __restrict__ df_,   const u16* __restrict__ dr_,
    const float* __restrict__ Dskf, const float* __restrict__ Dskr,
    const float* __restrict__ hin,
    u16* __restrict__ yf, u16* __restrict__ yr)
{
  const int e = blockIdx.x * 128 + threadIdx.x;
  const int c = blockIdx.y;
  const int dir = blockIdx.z >> 1, b = blockIdx.z & 1;
  const float* bc = dir ? bcr : bcf;
  const u16* x    = dir ? xr_ : xf_;
  const float* Al = dir ? Alr : Alf;
  const u16* dpre = dir ? dr_ : df_;
  const float dskip = (dir ? Dskr : Dskf)[e];

  float A20;
  const bool structured = a_check(Al, e, A20);

  const int g = (dir * 2 + b) * DI + e;
  const size_t cb = (size_t)c * NCHAN + (size_t)g * DS;
  const size_t m0 = (size_t)b * SEQ + (size_t)c * CT_;

  if (structured) {
    f32x2 h2[8];
    #pragma unroll
    for (int k = 0; k < 8; k++) h2[k] = *(const f32x2*)&hin[cb + 2 * k];
    #pragma unroll 2
    for (int t = 0; t < CT_; t++) {
      const size_t m = m0 + t;
      const float d  = bf2f(dpre[m * DI + e]);
      const float xv = bf2f(x[m * DI + e]);
      const float dbx = d * xv;
      const f32x4* bp = (const f32x4*)(bc + m * 32);
      const f32x4 b0 = bp[0], b1 = bp[1], b2 = bp[2], b3 = bp[3];
      const f32x4 c0 = bp[4], c1 = bp[5], c2 = bp[6], c3 = bp[7];
      const float q = fexp2(A20 * d), q2 = q * q, q4 = q2 * q2, q8 = q4 * q4;
      const f32x2 q2v = (f32x2){q2, q2}, q4v = (f32x2){q4, q4}, q8v = (f32x2){q8, q8};
      const f32x2 dbx2 = (f32x2){dbx, dbx};
      const f32x2 p0 = (f32x2){q, q2};
      const f32x2 p1 = p0 * q2v, p2 = p0 * q4v, p3 = p1 * q4v;
      const f32x2 p4 = p0 * q8v, p5 = p1 * q8v, p6 = p2 * q8v, p7 = p3 * q8v;
      f32x2 y2 = (f32x2){0.f, 0.f};
      h2[0] = p0 * h2[0] + dbx2 * (f32x2){b0[0], b0[1]};  y2 = y2 + h2[0] * (f32x2){c0[0], c0[1]};
      h2[1] = p1 * h2[1] + dbx2 * (f32x2){b0[2], b0[3]};  y2 = y2 + h2[1] * (f32x2){c0[2], c0[3]};
      h2[2] = p2 * h2[2] + dbx2 * (f32x2){b1[0], b1[1]};  y2 = y2 + h2[2] * (f32x2){c1[0], c1[1]};
      h2[3] = p3 * h2[3] + dbx2 * (f32x2){b1[2], b1[3]};  y2 = y2 + h2[3] * (f32x2){c1[2], c1[3]};
      h2[4] = p4 * h2[4] + dbx2 * (f32x2){b2[0], b2[1]};  y2 = y2 + h2[4] * (f32x2){c2[0], c2[1]};
      h2[5] = p5 * h2[5] + dbx2 * (f32x2){b2[2], b2[3]};  y2 = y2 + h2[5] * (f32x2){c2[2], c2[3]};
      h2[6] = p6 * h2[6] + dbx2 * (f32x2){b3[0], b3[1]};  y2 = y2 + h2[6] * (f32x2){c3[0], c3[1]};
      h2[7] = p7 * h2[7] + dbx2 * (f32x2){b3[2], b3[3]};  y2 = y2 + h2[7] * (f32x2){c3[2], c3[3]};
      const float yout = (y2[0] + y2[1]) + xv * dskip;
      if (dir == 0) {
        yf[m * DI + e] = f2bf(yout);
      } else {
        const size_t mo = (size_t)b * SEQ + (SEQ - 1 - (c * CT_ + t));
        yr[mo * DI + e] = f2bf(yout);
      }
    }
  } else {
    float A2[DS], h[DS];
    #pragma unroll
    for (int n = 0; n < DS; n++) A2[n] = -__expf(Al[e * DS + n]) * LOG2E;
    #pragma unroll
    for (int n = 0; n < DS; n++) h[n] = hin[cb + n];
    for (int t = 0; t < CT_; t++) {
      const size_t m = m0 + t;
      const float d  = bf2f(dpre[m * DI + e]);
      const float xv = bf2f(x[m * DI + e]);
      const float dbx = d * xv;
      float dAv[DS];
      dA_generic(d, A2, dAv);
      float y = 0.f;
      #pragma unroll
      for (int n = 0; n < DS; n++) {
        h[n] = dAv[n] * h[n] + dbx * bc[m * 32 + n];
        y += h[n] * bc[m * 32 + 16 + n];
      }
      const float yout = y + xv * dskip;
      if (dir == 0) {
        yf[m * DI + e] = f2bf(yout);
      } else {
        const size_t mo = (size_t)b * SEQ + (SEQ - 1 - (c * CT_ + t));
        yr[mo * DI + e] = f2bf(yout);
      }
    }
  }
}

// Elementwise combine: yf = (yf + yr) * sz, 8 bf16 per thread.
__global__ __launch_bounds__(256) void comb_k(
    u16* __restrict__ yfp, const u16* __restrict__ yrp, const u16* __restrict__ szp)
{
  const size_t i = ((size_t)blockIdx.x * 256 + threadIdx.x) * 8;
  union { uint4 v; u16 s[8]; } A, Bq, S, O;
  A.v  = *(const uint4*)(yfp + i);
  Bq.v = *(const uint4*)(yrp + i);
  S.v  = *(const uint4*)(szp + i);
  #pragma unroll
  for (int j = 0; j < 8; j++)
    O.s[j] = f2bf((bf2f(A.s[j]) + bf2f(Bq.s[j])) * bf2f(S.s[j]));
  *(uint4*)(yfp + i) = O.v;
}

// ---------------------------------------------------------------------------
// Legacy (low-ws) scan kernels: bf16 xdbl operands, on-the-fly delta.
// ---------------------------------------------------------------------------
__global__ __launch_bounds__(256) void scanA_k(
    const u16* __restrict__ xdblf_, const u16* __restrict__ xdblr_,
    const u16* __restrict__ xf_,    const u16* __restrict__ xr_,
    const float* __restrict__ Alf,  const float* __restrict__ Alr,
    const float* __restrict__ dtwf, const float* __restrict__ dtwr,
    const float* __restrict__ dtbf, const float* __restrict__ dtbr,
    float* __restrict__ sumdP, float* __restrict__ bP, int ct)
{
  const int e = blockIdx.x * 256 + threadIdx.x;
  const int c = blockIdx.y;
  const int dir = blockIdx.z >> 1, b = blockIdx.z & 1;
  const u16* xdbl = dir ? xdblr_ : xdblf_;
  const u16* x    = dir ? xr_ : xf_;
  const float* Al = dir ? Alr : Alf;

  float A2[DS], h[DS], dw[DTR];
  #pragma unroll
  for (int n = 0; n < DS; n++) { A2[n] = -__expf(Al[e * DS + n]) * LOG2E; h[n] = 0.f; }
  const float* dtw = dir ? dtwr : dtwf;
  #pragma unroll
  for (int r = 0; r < DTR; r += 4) {
    const float4 v = *(const float4*)(dtw + e * DTR + r);
    dw[r] = v.x; dw[r+1] = v.y; dw[r+2] = v.z; dw[r+3] = v.w;
  }
  const float bias = (dir ? dtbr : dtbf)[e];

  float sumd = 0.f;
  const size_t m0 = (size_t)b * SEQ + (size_t)c * ct;
  for (int t = 0; t < ct; t++) {
    const size_t m = m0 + t;
    union { uint4 v[4]; u16 s[32]; } DT;
    #pragma unroll
    for (int q = 0; q < 4; q++) DT.v[q] = ((const uint4*)(xdbl + m * 64))[q];
    float a0 = 0.f, a1 = 0.f, a2 = 0.f, a3 = 0.f;
    #pragma unroll
    for (int r = 0; r < DTR; r += 4) {
      a0 += bf2f(DT.s[r+0]) * dw[r+0];
      a1 += bf2f(DT.s[r+1]) * dw[r+1];
      a2 += bf2f(DT.s[r+2]) * dw[r+2];
      a3 += bf2f(DT.s[r+3]) * dw[r+3];
    }
    const float d = softplus_f(((a0 + a1) + (a2 + a3)) + bias);
    const float xv  = bf2f(x[m * DI + e]);
    const float dbx = d * xv;
    sumd += d;
    union { uint4 v[2]; u16 s[16]; } Bv;
    Bv.v[0] = ((const uint4*)(xdbl + m * 64 + 32))[0];
    Bv.v[1] = ((const uint4*)(xdbl + m * 64 + 32))[1];
    float dAv[DS];
    dA_generic(d, A2, dAv);
    #pragma unroll
    for (int n = 0; n < DS; n++)
      h[n] = dAv[n] * h[n] + dbx * bf2f(Bv.s[n]);
  }
  const int g = (dir * 2 + b) * DI + e;
  const size_t cb = (size_t)c * NCHAN + (size_t)g * DS;
  #pragma unroll
  for (int n = 0; n < DS; n++) bP[cb + n] = h[n];
  sumdP[(size_t)c * NG + g] = sumd;
}

template<int MODE>
__global__ __launch_bounds__(256) void scanC_k(
    const u16* __restrict__ xdblf_, const u16* __restrict__ xdblr_,
    const u16* __restrict__ xf_,    const u16* __restrict__ xr_,
    const float* __restrict__ Alf,  const float* __restrict__ Alr,
    const float* __restrict__ dtwf, const float* __restrict__ dtwr,
    const float* __restrict__ dtbf, const float* __restrict__ dtbr,
    const float* __restrict__ Dskf, const float* __restrict__ Dskr,
    const float* __restrict__ hin,
    u16* __restrict__ yf, u16* __restrict__ yr,
    const u16* __restrict__ szp, int ct)
{
  const int e = blockIdx.x * 256 + threadIdx.x;
  const int c = blockIdx.y;
  const int dir = (MODE == 2); const int b = blockIdx.z;
  const u16* xdbl = dir ? xdblr_ : xdblf_;
  const u16* x    = dir ? xr_ : xf_;
  const float* Al = dir ? Alr : Alf;
  const float dskip = (dir ? Dskr : Dskf)[e];

  float A2[DS], h[DS], dw[DTR];
  #pragma unroll
  for (int n = 0; n < DS; n++) A2[n] = -__expf(Al[e * DS + n]) * LOG2E;
  const float* dtw = dir ? dtwr : dtwf;
  #pragma unroll
  for (int r = 0; r < DTR; r += 4) {
    const float4 v = *(const float4*)(dtw + e * DTR + r);
    dw[r] = v.x; dw[r+1] = v.y; dw[r+2] = v.z; dw[r+3] = v.w;
  }
  const float bias = (dir ? dtbr : dtbf)[e];

  const int g = (dir * 2 + b) * DI + e;
  const size_t cb = (size_t)c * NCHAN + (size_t)g * DS;
  #pragma unroll
  for (int n = 0; n < DS; n++) h[n] = hin[cb + n];
  const size_t m0 = (size_t)b * SEQ + (size_t)c * ct;

  for (int t = 0; t < ct; t++) {
    const size_t m = m0 + t;
    union { uint4 v[4]; u16 s[32]; } BC;
    #pragma unroll
    for (int q = 0; q < 4; q++) BC.v[q] = ((const uint4*)(xdbl + m * 64 + 32))[q];
    union { uint4 v[4]; u16 s[32]; } DT;
    #pragma unroll
    for (int q = 0; q < 4; q++) DT.v[q] = ((const uint4*)(xdbl + m * 64))[q];
    float a0 = 0.f, a1 = 0.f, a2 = 0.f, a3 = 0.f;
    #pragma unroll
    for (int r = 0; r < DTR; r += 4) {
      a0 += bf2f(DT.s[r+0]) * dw[r+0];
      a1 += bf2f(DT.s[r+1]) * dw[r+1];
      a2 += bf2f(DT.s[r+2]) * dw[r+2];
      a3 += bf2f(DT.s[r+3]) * dw[r+3];
    }
    const float d = softplus_f(((a0 + a1) + (a2 + a3)) + bias);
    const float xv  = bf2f(x[m * DI + e]);
    const float dbx = d * xv;
    float dAv[DS];
    dA_generic(d, A2, dAv);
    float y = 0.f;
    #pragma unroll
    for (int n = 0; n < DS; n++) {
      h[n] = dAv[n] * h[n] + dbx * bf2f(BC.s[n]);
      y += h[n] * bf2f(BC.s[16 + n]);
    }
    const float yout = y + xv * dskip;
    if (MODE == 1) {
      yf[m * DI + e] = f2bf(yout);
    } else {
      const size_t mo = (size_t)b * SEQ + (SEQ - 1 - (c * ct + t));
      const size_t moi = mo * DI + e;
      yr[moi] = f2bf((bf2f(yf[moi]) + yout) * bf2f(szp[moi]));
    }
  }
}

// ---------------------------------------------------------------------------
extern "C" void kernel_launch(void* const* d_in, const int* in_sizes, int n_in,
                              void* d_out, int out_size, void* d_ws, size_t ws_size,
                              hipStream_t stream)
{
  (void)in_sizes; (void)n_in; (void)out_size;
  const float* u      = (const float*)d_in[0];
  const float* in_w   = (const float*)d_in[1];
  const float* out_w  = (const float*)d_in[2];
  const float* cw_f   = (const float*)d_in[3];
  const float* cb_f   = (const float*)d_in[4];
  const float* xw_f   = (const float*)d_in[5];
  const float* dtw_f  = (const float*)d_in[6];
  const float* dtb_f  = (const float*)d_in[7];
  const float* Alog_f = (const float*)d_in[8];
  const float* D_f    = (const float*)d_in[9];
  const float* cw_r   = (const float*)d_in[10];
  const float* cb_r   = (const float*)d_in[11];
  const float* xw_r   = (const float*)d_in[12];
  const float* dtw_r  = (const float*)d_in[13];
  const float* dtb_r  = (const float*)d_in[14];
  const float* Alog_r = (const float*)d_in[15];
  const float* D_r    = (const float*)d_in[16];

  const size_t mexe = (size_t)M_TOT * DI;          // 16.78M elements
  const size_t bc_bytes = (size_t)M_TOT * 32 * 4;  // 2.1 MB f32 BC per dir
  const size_t need_big =
      5 * (mexe * 2) + 2 * ((size_t)M_TOT * 64 * 2) + 2 * bc_bytes +
      (size_t)WU_TOT * 16 +
      (size_t)128 * NG * 4 + (size_t)128 * NCHAN * 4 + 64 * 256;
  const bool big = (ws_size >= need_big);
  const int nchunk = 64;               // CT = 128 for both paths
  const int ct = SEQ / nchunk;

  char* ws = (char*)d_ws;
  size_t off = 0;
  auto alloc = [&](size_t bytes) -> void* {
    void* p = ws + off;
    off += (bytes + 255) & ~(size_t)255;
    return p;
  };
  u16*   ubf   = (u16*)alloc(mexe * 2);            // bf16 u; dead after in_proj -> df
  u16*   xpre  = (u16*)alloc(mexe * 2);            // dead after conv -> yr
  u16*   xf    = (u16*)alloc(mexe * 2);            // x_f; in-place y_f / combined y
  u16*   xr    = (u16*)alloc(mexe * 2);
  u16*   xdblf = (u16*)alloc((size_t)M_TOT * 64 * 2);
  u16*   xdblr = (u16*)alloc((size_t)M_TOT * 64 * 2);
  float* bc32f = (float*)alloc(bc_bytes);          // f32 B/C operand, dir f
  float* bc32r = (float*)alloc(bc_bytes);
  u16*   wbf   = (u16*)alloc((size_t)WU_TOT * 16); // bf16 weight arena
  float* sumdP = (float*)alloc((size_t)128 * NG * 4);    // sized for <=128 chunks
  float* bP    = (float*)alloc((size_t)128 * NCHAN * 4);
  u16*   dr    = big ? (u16*)alloc(mexe * 2) : nullptr;
  u16*   df    = ubf;                              // alias (u dead after in_proj)
  u16*   szb   = (u16*)d_out;                      // silu(z) in d_out (dead before out_proj)

  // weight arena sub-pointers (units of 8 elems = 16 B)
  u16* winb  = wbf;
  u16* xwbf  = wbf + (size_t)WU_INW * 8;
  u16* xwbr  = xwbf + (size_t)WU_XW * 8;
  u16* dtwbf = xwbr + (size_t)WU_XW * 8;
  u16* dtwbr = dtwbf + (size_t)WU_DTW * 8;
  u16* outwb = dtwbr + (size_t)WU_DTW * 8;

  dim3 blk(256);
  // 0) convert u + weights to bf16.  u has M_TOT*DM = 8.39M elems -> 4096 blocks.
  cvt_k<<<dim3((unsigned)((size_t)M_TOT * DM / 8 / 256)), blk, 0, stream>>>(u, ubf);
  cvtw_k<<<dim3(WU_TOT / 256), blk, 0, stream>>>(in_w, xw_f, xw_r, dtw_f, dtw_r, out_w, wbf);
  // 1) in_proj (BK=64)
  gemm_k<128, 64, 0, false><<<dim3(128, 16), blk, 0, stream>>>(
      ubf, nullptr, DM, winb, nullptr, DM, xpre, nullptr, szb, nullptr, nullptr, nullptr, 0);
  // 2) depthwise conv + silu, both dirs in one pass
  conv2_k<<<dim3(SEQ / (2 * CLT), B_SZ), blk, 0, stream>>>(
      xpre, cw_f, cb_f, cw_r, cb_r, xf, xr);
  // 3) xproj (dual, BK=64): xdbl = x @ xproj_w^T ; n>=32 also stored f32 to bc32
  gemm_k<64, 64, 1, true><<<dim3(128, 1, 2), blk, 0, stream>>>(
      xf, xr, DI, xwbf, xwbr, DI, xdblf, xdblr, bc32f, bc32r, nullptr, nullptr, 64);

  if (big) {
    // 4) delta (dual, BK=32 since K=32)
    gemm_k<128, 32, 2, true><<<dim3(128, 8, 2), blk, 0, stream>>>(
        xdblf, xdblr, 64, dtwbf, dtwbr, DTR, df, dr, nullptr, nullptr, dtb_f, dtb_r, DI);
    // 5) scan (CT=128, nchunk=64)
    scanA2_k<128><<<dim3(8, nchunk, 4), dim3(128), 0, stream>>>(
        bc32f, bc32r, xf, xr, Alog_f, Alog_r, df, dr, sumdP, bP);
    scanB_k<<<dim3(NCHAN / 256), blk, 0, stream>>>(sumdP, bP, Alog_f, Alog_r, nchunk);
    scanC2_k<128><<<dim3(8, nchunk, 4), dim3(128), 0, stream>>>(
        bc32f, bc32r, xf, xr, Alog_f, Alog_r, df, dr, D_f, D_r, bP, xf, xpre);
    // 6) combine: yf = (yf + yr) * silu(z)
    comb_k<<<dim3((unsigned)(mexe / 8 / 256)), blk, 0, stream>>>(xf, xpre, szb);
    // 7) out_proj (BK=64) from combined xf
    gemm_k<128, 64, 3, false><<<dim3(128, 4), blk, 0, stream>>>(
        xf, nullptr, DI, outwb, nullptr, DI, d_out, nullptr, nullptr, nullptr, nullptr, nullptr, DM);
  } else {
    // legacy (low-ws) path
    scanA_k<<<dim3(4, nchunk, 4), blk, 0, stream>>>(
        xdblf, xdblr, xf, xr, Alog_f, Alog_r, dtw_f, dtw_r, dtb_f, dtb_r,
        sumdP, bP, ct);
    scanB_k<<<dim3(NCHAN / 256), blk, 0, stream>>>(sumdP, bP, Alog_f, Alog_r, nchunk);
    scanC_k<1><<<dim3(4, nchunk, 2), blk, 0, stream>>>(
        xdblf, xdblr, xf, xr, Alog_f, Alog_r, dtw_f, dtw_r, dtb_f, dtb_r,
        D_f, D_r, bP, xf, nullptr, nullptr, ct);
    scanC_k<2><<<dim3(4, nchunk, 2), blk, 0, stream>>>(
        xdblf, xdblr, xf, xr, Alog_f, Alog_r, dtw_f, dtw_r, dtb_f, dtb_r,
        D_f, D_r, bP, xf, xpre, szb, ct);
    gemm_k<128, 64, 3, false><<<dim3(128, 4), blk, 0, stream>>>(
        xpre, nullptr, DI, outwb, nullptr, DI, d_out, nullptr, nullptr, nullptr, nullptr, nullptr, DM);
  }
}

// Round 18
// 350.553 us; speedup vs baseline: 1.0709x; 1.0089x over previous
//
#include <hip/hip_runtime.h>
#include <hip/hip_bf16.h>
#include <math.h>

#define B_SZ 2
#define SEQ  8192
#define DM   512
#define DI   1024
#define DS   16
#define DTR  32
#define M_TOT (B_SZ*SEQ)        // 16384 positions
#define LOG2E 1.44269504088896f
#define NCHAN  (4*DI*DS)        // 65536 scan channels ((dir*2+b)*DI+e)*DS+n
#define NG     (4*DI)           // 4096 (dir,b,e) groups
#define CLT    8                // conv timesteps per thread

typedef __attribute__((ext_vector_type(8))) short bf16x8;
typedef __attribute__((ext_vector_type(4))) float f32x4;
typedef __attribute__((ext_vector_type(2))) float f32x2;
typedef unsigned short u16;

__device__ __forceinline__ float bf2f(u16 u){
  union { unsigned u; float f; } v; v.u = ((unsigned)u) << 16; return v.f;
}
__device__ __forceinline__ u16 f2bf(float f){
  union { float f; unsigned u; } v; v.f = f;
  unsigned r = v.u + 0x7FFFu + ((v.u >> 16) & 1u);
  return (u16)(r >> 16);
}
__device__ __forceinline__ float silu_f(float x){ return x / (1.f + __expf(-x)); }
__device__ __forceinline__ float softplus_f(float x){
  return (x > 15.f) ? x : __logf(1.f + __expf(x));
}
__device__ __forceinline__ float fexp2(float x){ return __builtin_amdgcn_exp2f(x); }

__device__ __forceinline__ void dA_generic(float d, const float* A2, float* dAv){
  #pragma unroll
  for (int n = 0; n < DS; n++) dAv[n] = fexp2(A2[n] * d);
}

// ---------------------------------------------------------------------------
// f32 -> bf16 bulk convert, 8 elems/thread.
// ---------------------------------------------------------------------------
__global__ __launch_bounds__(256) void cvt_k(
    const float* __restrict__ s, u16* __restrict__ d)
{
  const size_t i = (size_t)blockIdx.x * 256 + threadIdx.x;
  const float4 a = ((const float4*)s)[i * 2];
  const float4 b = ((const float4*)s)[i * 2 + 1];
  union { uint4 v; u16 h[8]; } o;
  o.h[0] = f2bf(a.x); o.h[1] = f2bf(a.y); o.h[2] = f2bf(a.z); o.h[3] = f2bf(a.w);
  o.h[4] = f2bf(b.x); o.h[5] = f2bf(b.y); o.h[6] = f2bf(b.z); o.h[7] = f2bf(b.w);
  ((uint4*)d)[i] = o.v;
}

// Packed weight convert: 6 tensors -> one bf16 arena. Unit = 8 elems.
#define WU_INW  131072
#define WU_XW   8192
#define WU_DTW  4096
#define WU_OUTW 65536
#define WU_TOT  (WU_INW + 2*WU_XW + 2*WU_DTW + WU_OUTW)   // 221184
__global__ __launch_bounds__(256) void cvtw_k(
    const float* __restrict__ inw, const float* __restrict__ xwf,
    const float* __restrict__ xwr, const float* __restrict__ dtwf,
    const float* __restrict__ dtwr, const float* __restrict__ outw,
    u16* __restrict__ dst)
{
  int i = blockIdx.x * 256 + threadIdx.x;
  const float* s;
  int base = 0;
  if (i < WU_INW) { s = inw; }
  else if ((i -= WU_INW) < WU_XW) { s = xwf; base = WU_INW; }
  else if ((i -= WU_XW) < WU_XW)  { s = xwr; base = WU_INW + WU_XW; }
  else if ((i -= WU_XW) < WU_DTW) { s = dtwf; base = WU_INW + 2*WU_XW; }
  else if ((i -= WU_DTW) < WU_DTW){ s = dtwr; base = WU_INW + 2*WU_XW + WU_DTW; }
  else { i -= WU_DTW; s = outw; base = WU_INW + 2*WU_XW + 2*WU_DTW; }
  const float4 a = ((const float4*)s)[i * 2];
  const float4 b = ((const float4*)s)[i * 2 + 1];
  union { uint4 v; u16 h[8]; } o;
  o.h[0] = f2bf(a.x); o.h[1] = f2bf(a.y); o.h[2] = f2bf(a.z); o.h[3] = f2bf(a.w);
  o.h[4] = f2bf(b.x); o.h[5] = f2bf(b.y); o.h[6] = f2bf(b.z); o.h[7] = f2bf(b.w);
  ((uint4*)(dst))[base + i] = o.v;
}

// ---------------------------------------------------------------------------
// MFMA bf16 GEMM, global_load_lds staging + XOR swizzle, templated BK.
// EPI: 0 = split xz; 1 = bf16 + f32 side-store n>=32; 2 = softplus+bias; 3 = f32
// ---------------------------------------------------------------------------
template<int BN, int BK, int EPI, bool DUAL>
__global__ __launch_bounds__(256) void gemm_k(
    const u16* __restrict__ Ap,  const u16* __restrict__ Ap2, int lda,
    const u16* __restrict__ Bw,  const u16* __restrict__ Bw2, int K,
    void* __restrict__ out0, void* __restrict__ out02,
    void* __restrict__ out1, void* __restrict__ out12,
    const float* __restrict__ bias, const float* __restrict__ bias2, int ldo)
{
  constexpr int BM = 128;
  constexpr int NSLOT = BK / 8;        // 16B slots per LDS row
  constexpr int RPI   = 512 / BK;      // rows covered by one 1KB wave-issue
  __shared__ __align__(16) u16 As[BM * BK];
  __shared__ __align__(16) u16 Bs[BN * BK];
  const int tid  = threadIdx.x;
  const int lane = tid & 63, wid = tid >> 6;
  const int mt = blockIdx.x, nt = blockIdx.y;
  const int z  = DUAL ? blockIdx.z : 0;
  const u16* A = z ? Ap2 : Ap;
  const u16* W = z ? Bw2 : Bw;
  void* o0 = z ? out02 : out0;
  void* o1 = z ? out12 : out1;
  const float* bi = z ? bias2 : bias;

  constexpr int FM = (BN == 128) ? 4 : 2;
  const int wm = (BN == 128) ? ((wid >> 1) * 64) : (wid * 32);
  const int wn = (BN == 128) ? ((wid & 1) * 64) : 0;

  f32x4 acc[FM][4];
  #pragma unroll
  for (int i = 0; i < FM; i++)
    #pragma unroll
    for (int j = 0; j < 4; j++)
      acc[i][j] = (f32x4){0.f, 0.f, 0.f, 0.f};

  const int sr   = lane / NSLOT;                 // row within RPI-row chunk
  const int slot = lane % NSLOT;
  const int skey = (BK == 32) ? ((sr >> 1) & 3) : (sr & 7);
  const int sc   = (slot ^ skey) * 8;            // pre-swizzled source col

  for (int k0 = 0; k0 < K; k0 += BK) {
    #pragma unroll
    for (int j = 0; j < BM / RPI / 4; j++) {     // A issues per wave
      const int chunk = wid * (BM / RPI / 4) + j;
      const u16* src = A + (size_t)(mt * BM + chunk * RPI + sr) * lda + (k0 + sc);
      __builtin_amdgcn_global_load_lds(
          (const __attribute__((address_space(1))) void*)src,
          (__attribute__((address_space(3))) void*)(As + chunk * 512), 16, 0, 0);
    }
    #pragma unroll
    for (int j = 0; j < BN / RPI / 4; j++) {     // B issues per wave
      const int chunk = wid * (BN / RPI / 4) + j;
      const u16* src = W + (size_t)(nt * BN + chunk * RPI + sr) * K + (k0 + sc);
      __builtin_amdgcn_global_load_lds(
          (const __attribute__((address_space(1))) void*)src,
          (__attribute__((address_space(3))) void*)(Bs + chunk * 512), 16, 0, 0);
    }
    __syncthreads();

    const int row  = lane & 15;
    const int rkey = (BK == 32) ? ((row >> 1) & 3) : (row & 7);
    #pragma unroll
    for (int kh = 0; kh < BK / 32; kh++) {
      const int sl = (kh * 4 + (lane >> 4)) ^ rkey;   // swizzled 16B slot
      bf16x8 af[FM], bfr[4];
      #pragma unroll
      for (int i = 0; i < FM; i++)
        af[i] = *(const bf16x8*)&As[(wm + i * 16 + row) * BK + sl * 8];
      #pragma unroll
      for (int j = 0; j < 4; j++)
        bfr[j] = *(const bf16x8*)&Bs[(wn + j * 16 + row) * BK + sl * 8];
      #pragma unroll
      for (int i = 0; i < FM; i++)
        #pragma unroll
        for (int j = 0; j < 4; j++)
          acc[i][j] = __builtin_amdgcn_mfma_f32_16x16x32_bf16(af[i], bfr[j], acc[i][j], 0, 0, 0);
    }
    __syncthreads();
  }

  const int rb4 = (lane >> 4) * 4, col = lane & 15;
  #pragma unroll
  for (int i = 0; i < FM; i++) {
    #pragma unroll
    for (int j = 0; j < 4; j++) {
      #pragma unroll
      for (int r = 0; r < 4; r++) {
        const int m = mt * BM + wm + i * 16 + rb4 + r;
        const int n = nt * BN + wn + j * 16 + col;
        const float v = acc[i][j][r];
        if (EPI == 0) {
          if (n < DI) ((u16*)o0)[(size_t)m * DI + n] = f2bf(v);
          else        ((u16*)out1)[(size_t)m * DI + (n - DI)] = f2bf(silu_f(v));
        } else if (EPI == 1) {
          ((u16*)o0)[(size_t)m * ldo + n] = f2bf(v);
          if (n >= 32) ((float*)o1)[(size_t)m * 32 + (n - 32)] = v;
        } else if (EPI == 2) {
          ((u16*)o0)[(size_t)m * ldo + n] = f2bf(softplus_f(v + bi[n]));
        } else {
          ((float*)o0)[(size_t)m * ldo + n] = v;
        }
      }
    }
  }
}

// ---------------------------------------------------------------------------
// Depthwise causal conv(4) + bias + silu, BOTH directions in one ascending pass.
// ---------------------------------------------------------------------------
__global__ __launch_bounds__(256) void conv2_k(
    const u16* __restrict__ xpre,
    const float* __restrict__ wf, const float* __restrict__ bf_,
    const float* __restrict__ wr, const float* __restrict__ br_,
    u16* __restrict__ xf, u16* __restrict__ xr)
{
  const int tid  = threadIdx.x;
  const int et   = tid & 127;
  const int lsub = tid >> 7;
  const int e0 = et * 8;
  const int b  = blockIdx.y;
  const int l0 = (blockIdx.x * 2 + lsub) * CLT;
  const size_t base = (size_t)b * SEQ * DI + e0;

  float4 wf4[8], wr4[8];
  float  bfv[8], brv[8];
  #pragma unroll
  for (int j = 0; j < 8; j++) {
    wf4[j] = *(const float4*)(wf + (e0 + j) * 4);
    wr4[j] = *(const float4*)(wr + (e0 + j) * 4);
    bfv[j] = bf_[e0 + j];
    brv[j] = br_[e0 + j];
  }

  float c0[8], c1[8], c2[8];
  auto loadv = [&](int l, float* dst) {
    if (l < 0 || l >= SEQ) {
      #pragma unroll
      for (int j = 0; j < 8; j++) dst[j] = 0.f;
      return;
    }
    union { uint4 v; u16 s[8]; } t;
    t.v = *(const uint4*)(xpre + base + (size_t)l * DI);
    #pragma unroll
    for (int j = 0; j < 8; j++) dst[j] = bf2f(t.s[j]);
  };
  loadv(l0 - 3, c0); loadv(l0 - 2, c1); loadv(l0 - 1, c2);

  #pragma unroll
  for (int i = 0; i < CLT + 3; i++) {
    const int l = l0 + i;
    float cn[8];
    loadv(l, cn);
    if (i < CLT) {
      union { uint4 v; u16 s[8]; } o;
      #pragma unroll
      for (int j = 0; j < 8; j++) {
        const float v = bfv[j] + wf4[j].x * c0[j] + wf4[j].y * c1[j]
                               + wf4[j].z * c2[j] + wf4[j].w * cn[j];
        o.s[j] = f2bf(silu_f(v));
      }
      *(uint4*)(xf + base + (size_t)l * DI) = o.v;
    }
    if (i >= 3) {
      const int lr = l - 3;
      union { uint4 v; u16 s[8]; } o;
      #pragma unroll
      for (int j = 0; j < 8; j++) {
        const float v = brv[j] + wr4[j].w * c0[j] + wr4[j].z * c1[j]
                               + wr4[j].y * c2[j] + wr4[j].x * cn[j];
        o.s[j] = f2bf(silu_f(v));
      }
      *(uint4*)(xr + base + (size_t)(SEQ - 1 - lr) * DI) = o.v;
    }
    #pragma unroll
    for (int j = 0; j < 8; j++) { c0[j] = c1[j]; c1[j] = c2[j]; c2[j] = cn[j]; }
  }
}

// structured-A check + A20 for channel e
__device__ __forceinline__ bool a_check(const float* Al, int e, float& A20){
  float A2[DS];
  #pragma unroll
  for (int n = 0; n < DS; n++) A2[n] = -__expf(Al[e * DS + n]) * LOG2E;
  A20 = A2[0];
  bool st = true;
  #pragma unroll
  for (int n = 1; n < DS; n++)
    st = st && (fabsf(A2[n] - (float)(n + 1) * A20) <= 1e-3f * fabsf(A2[n]));
  return st;
}

// ---------------------------------------------------------------------------
// Scan pass A: CT=128 per thread, but emits carries at HALF-chunk (64-step)
// granularity: bP[2c] = half carry (h after 64 steps from 0),
//              bP[2c+1] = full carry (h after 128 steps from 0),
// sumdP[c] = full-chunk sum(delta), sumdP[64+c] = half-chunk sum(delta).
// grid: (8, 64, 4=dir*2+b), 128 thr
// ---------------------------------------------------------------------------
template<int CT_>
__global__ __launch_bounds__(128) void scanA2_k(
    const float* __restrict__ bcf, const float* __restrict__ bcr,
    const u16* __restrict__ xf_,   const u16* __restrict__ xr_,
    const float* __restrict__ Alf, const float* __restrict__ Alr,
    const u16* __restrict__ df_,   const u16* __restrict__ dr_,
    float* __restrict__ sumdP, float* __restrict__ bP)
{
  constexpr int HF = CT_ / 2;
  const int e = blockIdx.x * 128 + threadIdx.x;
  const int c = blockIdx.y;
  const int dir = blockIdx.z >> 1, b = blockIdx.z & 1;
  const float* bc = dir ? bcr : bcf;
  const u16* x    = dir ? xr_ : xf_;
  const float* Al = dir ? Alr : Alf;
  const u16* dpre = dir ? dr_ : df_;

  float A20;
  const bool structured = a_check(Al, e, A20);

  float sumd = 0.f, sumdH = 0.f;
  const size_t m0 = (size_t)b * SEQ + (size_t)c * CT_;
  const int g = (dir * 2 + b) * DI + e;
  const size_t cb0 = (size_t)(2 * c)     * NCHAN + (size_t)g * DS;  // half carry
  const size_t cb1 = (size_t)(2 * c + 1) * NCHAN + (size_t)g * DS;  // full carry

  if (structured) {
    f32x2 h2[8], hH[8];
    #pragma unroll
    for (int k = 0; k < 8; k++) h2[k] = (f32x2){0.f, 0.f};
    auto step = [&](int t) {
      const size_t m = m0 + t;
      const float d  = bf2f(dpre[m * DI + e]);
      const float xv = bf2f(x[m * DI + e]);
      const float dbx = d * xv;
      sumd += d;
      const f32x4* bp = (const f32x4*)(bc + m * 32);
      const f32x4 b0 = bp[0], b1 = bp[1], b2 = bp[2], b3 = bp[3];
      const float q = fexp2(A20 * d), q2 = q * q, q4 = q2 * q2, q8 = q4 * q4;
      const f32x2 q2v = (f32x2){q2, q2}, q4v = (f32x2){q4, q4}, q8v = (f32x2){q8, q8};
      const f32x2 dbx2 = (f32x2){dbx, dbx};
      const f32x2 p0 = (f32x2){q, q2};
      const f32x2 p1 = p0 * q2v, p2 = p0 * q4v, p3 = p1 * q4v;
      const f32x2 p4 = p0 * q8v, p5 = p1 * q8v, p6 = p2 * q8v, p7 = p3 * q8v;
      h2[0] = p0 * h2[0] + dbx2 * (f32x2){b0[0], b0[1]};
      h2[1] = p1 * h2[1] + dbx2 * (f32x2){b0[2], b0[3]};
      h2[2] = p2 * h2[2] + dbx2 * (f32x2){b1[0], b1[1]};
      h2[3] = p3 * h2[3] + dbx2 * (f32x2){b1[2], b1[3]};
      h2[4] = p4 * h2[4] + dbx2 * (f32x2){b2[0], b2[1]};
      h2[5] = p5 * h2[5] + dbx2 * (f32x2){b2[2], b2[3]};
      h2[6] = p6 * h2[6] + dbx2 * (f32x2){b3[0], b3[1]};
      h2[7] = p7 * h2[7] + dbx2 * (f32x2){b3[2], b3[3]};
    };
    #pragma unroll 2
    for (int t = 0; t < HF; t++) step(t);
    #pragma unroll
    for (int k = 0; k < 8; k++) hH[k] = h2[k];
    sumdH = sumd;
    #pragma unroll 2
    for (int t = HF; t < CT_; t++) step(t);
    #pragma unroll
    for (int k = 0; k < 8; k++) {
      *(f32x2*)&bP[cb0 + 2 * k] = hH[k];
      *(f32x2*)&bP[cb1 + 2 * k] = h2[k];
    }
  } else {
    float A2[DS], h[DS], hH[DS];
    #pragma unroll
    for (int n = 0; n < DS; n++) { A2[n] = -__expf(Al[e * DS + n]) * LOG2E; h[n] = 0.f; }
    auto step = [&](int t) {
      const size_t m = m0 + t;
      const float d  = bf2f(dpre[m * DI + e]);
      const float xv = bf2f(x[m * DI + e]);
      const float dbx = d * xv;
      sumd += d;
      float dAv[DS];
      dA_generic(d, A2, dAv);
      #pragma unroll
      for (int n = 0; n < DS; n++)
        h[n] = dAv[n] * h[n] + dbx * bc[m * 32 + n];
    };
    for (int t = 0; t < HF; t++) step(t);
    #pragma unroll
    for (int n = 0; n < DS; n++) hH[n] = h[n];
    sumdH = sumd;
    for (int t = HF; t < CT_; t++) step(t);
    #pragma unroll
    for (int n = 0; n < DS; n++) {
      bP[cb0 + n] = hH[n];
      bP[cb1 + n] = h[n];
    }
  }
  sumdP[(size_t)c * NG + g]        = sumd;   // full-chunk
  sumdP[(size_t)(64 + c) * NG + g] = sumdH;  // half-chunk
}

// ---------------------------------------------------------------------------
// Scan pass B (big path): chain 64 full-chunk carries, emit h_in at 64-step
// granularity into bP[2c], bP[2c+1] (in place; read-before-write per c).
// ---------------------------------------------------------------------------
__global__ __launch_bounds__(256) void scanB2_k(
    const float* __restrict__ sumdP, float* __restrict__ bP,
    const float* __restrict__ Alog_f, const float* __restrict__ Alog_r)
{
  const int ch = blockIdx.x * 256 + threadIdx.x;   // 0..65535
  const int g = ch >> 4, n = ch & 15;
  const int dir = g >> 11, e = g & (DI - 1);
  const float* Al = dir ? Alog_r : Alog_f;
  const float A2 = -__expf(Al[e * DS + n]) * LOG2E;
  float h = 0.f;
  for (int c = 0; c < 64; c++) {
    const float sF = sumdP[(size_t)c * NG + g];
    const float sH = sumdP[(size_t)(64 + c) * NG + g];
    const size_t i0 = (size_t)(2 * c) * NCHAN + ch;
    const size_t i1 = i0 + NCHAN;
    const float cH = bP[i0], cF = bP[i1];
    bP[i0] = h;                             // h_in for sub-chunk 2c
    bP[i1] = fexp2(A2 * sH) * h + cH;       // h_in for sub-chunk 2c+1
    h = fexp2(A2 * sF) * h + cF;
  }
}

// Legacy scan pass B: sequential over nchunk contiguous chunks.
__global__ __launch_bounds__(256) void scanB_k(
    const float* __restrict__ sumdP, float* __restrict__ bP,
    const float* __restrict__ Alog_f, const float* __restrict__ Alog_r, int nchunk)
{
  const int ch = blockIdx.x * 256 + threadIdx.x;   // 0..65535
  const int g = ch >> 4, n = ch & 15;
  const int dir = g >> 11, e = g & (DI - 1);
  const float* Al = dir ? Alog_r : Alog_f;
  const float A2 = -__expf(Al[e * DS + n]) * LOG2E;
  float h = 0.f;
  for (int c = 0; c < nchunk; c++) {
    const float a = fexp2(A2 * sumdP[(size_t)c * NG + g]);
    const size_t i = (size_t)c * NCHAN + ch;
    const float bb = bP[i];
    bP[i] = h;              // h_in for chunk c
    h = a * h + bb;
  }
}

// ---------------------------------------------------------------------------
// Big-path scan pass C (merged dirs): emit y (+ x*D). CT compile-time.
// dir0 -> yf[m] (in place over x_f); dir1 -> yr[mo] (mo = flipped).
// grid: (8, NCHUNKC, 4), 128 thr
// ---------------------------------------------------------------------------
template<int CT_>
__global__ __launch_bounds__(128) void scanC2_k(
    const float* __restrict__ bcf, const float* __restrict__ bcr,
    const u16* __restrict__ xf_,   const u16* __restrict__ xr_,
    const float* __restrict__ Alf, const float* __restrict__ Alr,
    const u16* __restrict__ df_,   const u16* __restrict__ dr_,
    const float* __restrict__ Dskf, const float* __restrict__ Dskr,
    const float* __restrict__ hin,
    u16* __restrict__ yf, u16* __restrict__ yr)
{
  const int e = blockIdx.x * 128 + threadIdx.x;
  const int c = blockIdx.y;
  const int dir = blockIdx.z >> 1, b = blockIdx.z & 1;
  const float* bc = dir ? bcr : bcf;
  const u16* x    = dir ? xr_ : xf_;
  const float* Al = dir ? Alr : Alf;
  const u16* dpre = dir ? dr_ : df_;
  const float dskip = (dir ? Dskr : Dskf)[e];

  float A20;
  const bool structured = a_check(Al, e, A20);

  const int g = (dir * 2 + b) * DI + e;
  const size_t cb = (size_t)c * NCHAN + (size_t)g * DS;
  const size_t m0 = (size_t)b * SEQ + (size_t)c * CT_;

  if (structured) {
    f32x2 h2[8];
    #pragma unroll
    for (int k = 0; k < 8; k++) h2[k] = *(const f32x2*)&hin[cb + 2 * k];
    #pragma unroll 2
    for (int t = 0; t < CT_; t++) {
      const size_t m = m0 + t;
      const float d  = bf2f(dpre[m * DI + e]);
      const float xv = bf2f(x[m * DI + e]);
      const float dbx = d * xv;
      const f32x4* bp = (const f32x4*)(bc + m * 32);
      const f32x4 b0 = bp[0], b1 = bp[1], b2 = bp[2], b3 = bp[3];
      const f32x4 c0 = bp[4], c1 = bp[5], c2 = bp[6], c3 = bp[7];
      const float q = fexp2(A20 * d), q2 = q * q, q4 = q2 * q2, q8 = q4 * q4;
      const f32x2 q2v = (f32x2){q2, q2}, q4v = (f32x2){q4, q4}, q8v = (f32x2){q8, q8};
      const f32x2 dbx2 = (f32x2){dbx, dbx};
      const f32x2 p0 = (f32x2){q, q2};
      const f32x2 p1 = p0 * q2v, p2 = p0 * q4v, p3 = p1 * q4v;
      const f32x2 p4 = p0 * q8v, p5 = p1 * q8v, p6 = p2 * q8v, p7 = p3 * q8v;
      f32x2 y2 = (f32x2){0.f, 0.f};
      h2[0] = p0 * h2[0] + dbx2 * (f32x2){b0[0], b0[1]};  y2 = y2 + h2[0] * (f32x2){c0[0], c0[1]};
      h2[1] = p1 * h2[1] + dbx2 * (f32x2){b0[2], b0[3]};  y2 = y2 + h2[1] * (f32x2){c0[2], c0[3]};
      h2[2] = p2 * h2[2] + dbx2 * (f32x2){b1[0], b1[1]};  y2 = y2 + h2[2] * (f32x2){c1[0], c1[1]};
      h2[3] = p3 * h2[3] + dbx2 * (f32x2){b1[2], b1[3]};  y2 = y2 + h2[3] * (f32x2){c1[2], c1[3]};
      h2[4] = p4 * h2[4] + dbx2 * (f32x2){b2[0], b2[1]};  y2 = y2 + h2[4] * (f32x2){c2[0], c2[1]};
      h2[5] = p5 * h2[5] + dbx2 * (f32x2){b2[2], b2[3]};  y2 = y2 + h2[5] * (f32x2){c2[2], c2[3]};
      h2[6] = p6 * h2[6] + dbx2 * (f32x2){b3[0], b3[1]};  y2 = y2 + h2[6] * (f32x2){c3[0], c3[1]};
      h2[7] = p7 * h2[7] + dbx2 * (f32x2){b3[2], b3[3]};  y2 = y2 + h2[7] * (f32x2){c3[2], c3[3]};
      const float yout = (y2[0] + y2[1]) + xv * dskip;
      if (dir == 0) {
        yf[m * DI + e] = f2bf(yout);
      } else {
        const size_t mo = (size_t)b * SEQ + (SEQ - 1 - (c * CT_ + t));
        yr[mo * DI + e] = f2bf(yout);
      }
    }
  } else {
    float A2[DS], h[DS];
    #pragma unroll
    for (int n = 0; n < DS; n++) A2[n] = -__expf(Al[e * DS + n]) * LOG2E;
    #pragma unroll
    for (int n = 0; n < DS; n++) h[n] = hin[cb + n];
    for (int t = 0; t < CT_; t++) {
      const size_t m = m0 + t;
      const float d  = bf2f(dpre[m * DI + e]);
      const float xv = bf2f(x[m * DI + e]);
      const float dbx = d * xv;
      float dAv[DS];
      dA_generic(d, A2, dAv);
      float y = 0.f;
      #pragma unroll
      for (int n = 0; n < DS; n++) {
        h[n] = dAv[n] * h[n] + dbx * bc[m * 32 + n];
        y += h[n] * bc[m * 32 + 16 + n];
      }
      const float yout = y + xv * dskip;
      if (dir == 0) {
        yf[m * DI + e] = f2bf(yout);
      } else {
        const size_t mo = (size_t)b * SEQ + (SEQ - 1 - (c * CT_ + t));
        yr[mo * DI + e] = f2bf(yout);
      }
    }
  }
}

// Elementwise combine: yf = (yf + yr) * sz, 8 bf16 per thread.
__global__ __launch_bounds__(256) void comb_k(
    u16* __restrict__ yfp, const u16* __restrict__ yrp, const u16* __restrict__ szp)
{
  const size_t i = ((size_t)blockIdx.x * 256 + threadIdx.x) * 8;
  union { uint4 v; u16 s[8]; } A, Bq, S, O;
  A.v  = *(const uint4*)(yfp + i);
  Bq.v = *(const uint4*)(yrp + i);
  S.v  = *(const uint4*)(szp + i);
  #pragma unroll
  for (int j = 0; j < 8; j++)
    O.s[j] = f2bf((bf2f(A.s[j]) + bf2f(Bq.s[j])) * bf2f(S.s[j]));
  *(uint4*)(yfp + i) = O.v;
}

// ---------------------------------------------------------------------------
// Legacy (low-ws) scan kernels: bf16 xdbl operands, on-the-fly delta.
// ---------------------------------------------------------------------------
__global__ __launch_bounds__(256) void scanA_k(
    const u16* __restrict__ xdblf_, const u16* __restrict__ xdblr_,
    const u16* __restrict__ xf_,    const u16* __restrict__ xr_,
    const float* __restrict__ Alf,  const float* __restrict__ Alr,
    const float* __restrict__ dtwf, const float* __restrict__ dtwr,
    const float* __restrict__ dtbf, const float* __restrict__ dtbr,
    float* __restrict__ sumdP, float* __restrict__ bP, int ct)
{
  const int e = blockIdx.x * 256 + threadIdx.x;
  const int c = blockIdx.y;
  const int dir = blockIdx.z >> 1, b = blockIdx.z & 1;
  const u16* xdbl = dir ? xdblr_ : xdblf_;
  const u16* x    = dir ? xr_ : xf_;
  const float* Al = dir ? Alr : Alf;

  float A2[DS], h[DS], dw[DTR];
  #pragma unroll
  for (int n = 0; n < DS; n++) { A2[n] = -__expf(Al[e * DS + n]) * LOG2E; h[n] = 0.f; }
  const float* dtw = dir ? dtwr : dtwf;
  #pragma unroll
  for (int r = 0; r < DTR; r += 4) {
    const float4 v = *(const float4*)(dtw + e * DTR + r);
    dw[r] = v.x; dw[r+1] = v.y; dw[r+2] = v.z; dw[r+3] = v.w;
  }
  const float bias = (dir ? dtbr : dtbf)[e];

  float sumd = 0.f;
  const size_t m0 = (size_t)b * SEQ + (size_t)c * ct;
  for (int t = 0; t < ct; t++) {
    const size_t m = m0 + t;
    union { uint4 v[4]; u16 s[32]; } DT;
    #pragma unroll
    for (int q = 0; q < 4; q++) DT.v[q] = ((const uint4*)(xdbl + m * 64))[q];
    float a0 = 0.f, a1 = 0.f, a2 = 0.f, a3 = 0.f;
    #pragma unroll
    for (int r = 0; r < DTR; r += 4) {
      a0 += bf2f(DT.s[r+0]) * dw[r+0];
      a1 += bf2f(DT.s[r+1]) * dw[r+1];
      a2 += bf2f(DT.s[r+2]) * dw[r+2];
      a3 += bf2f(DT.s[r+3]) * dw[r+3];
    }
    const float d = softplus_f(((a0 + a1) + (a2 + a3)) + bias);
    const float xv  = bf2f(x[m * DI + e]);
    const float dbx = d * xv;
    sumd += d;
    union { uint4 v[2]; u16 s[16]; } Bv;
    Bv.v[0] = ((const uint4*)(xdbl + m * 64 + 32))[0];
    Bv.v[1] = ((const uint4*)(xdbl + m * 64 + 32))[1];
    float dAv[DS];
    dA_generic(d, A2, dAv);
    #pragma unroll
    for (int n = 0; n < DS; n++)
      h[n] = dAv[n] * h[n] + dbx * bf2f(Bv.s[n]);
  }
  const int g = (dir * 2 + b) * DI + e;
  const size_t cb = (size_t)c * NCHAN + (size_t)g * DS;
  #pragma unroll
  for (int n = 0; n < DS; n++) bP[cb + n] = h[n];
  sumdP[(size_t)c * NG + g] = sumd;
}

template<int MODE>
__global__ __launch_bounds__(256) void scanC_k(
    const u16* __restrict__ xdblf_, const u16* __restrict__ xdblr_,
    const u16* __restrict__ xf_,    const u16* __restrict__ xr_,
    const float* __restrict__ Alf,  const float* __restrict__ Alr,
    const float* __restrict__ dtwf, const float* __restrict__ dtwr,
    const float* __restrict__ dtbf, const float* __restrict__ dtbr,
    const float* __restrict__ Dskf, const float* __restrict__ Dskr,
    const float* __restrict__ hin,
    u16* __restrict__ yf, u16* __restrict__ yr,
    const u16* __restrict__ szp, int ct)
{
  const int e = blockIdx.x * 256 + threadIdx.x;
  const int c = blockIdx.y;
  const int dir = (MODE == 2); const int b = blockIdx.z;
  const u16* xdbl = dir ? xdblr_ : xdblf_;
  const u16* x    = dir ? xr_ : xf_;
  const float* Al = dir ? Alr : Alf;
  const float dskip = (dir ? Dskr : Dskf)[e];

  float A2[DS], h[DS], dw[DTR];
  #pragma unroll
  for (int n = 0; n < DS; n++) A2[n] = -__expf(Al[e * DS + n]) * LOG2E;
  const float* dtw = dir ? dtwr : dtwf;
  #pragma unroll
  for (int r = 0; r < DTR; r += 4) {
    const float4 v = *(const float4*)(dtw + e * DTR + r);
    dw[r] = v.x; dw[r+1] = v.y; dw[r+2] = v.z; dw[r+3] = v.w;
  }
  const float bias = (dir ? dtbr : dtbf)[e];

  const int g = (dir * 2 + b) * DI + e;
  const size_t cb = (size_t)c * NCHAN + (size_t)g * DS;
  #pragma unroll
  for (int n = 0; n < DS; n++) h[n] = hin[cb + n];
  const size_t m0 = (size_t)b * SEQ + (size_t)c * ct;

  for (int t = 0; t < ct; t++) {
    const size_t m = m0 + t;
    union { uint4 v[4]; u16 s[32]; } BC;
    #pragma unroll
    for (int q = 0; q < 4; q++) BC.v[q] = ((const uint4*)(xdbl + m * 64 + 32))[q];
    union { uint4 v[4]; u16 s[32]; } DT;
    #pragma unroll
    for (int q = 0; q < 4; q++) DT.v[q] = ((const uint4*)(xdbl + m * 64))[q];
    float a0 = 0.f, a1 = 0.f, a2 = 0.f, a3 = 0.f;
    #pragma unroll
    for (int r = 0; r < DTR; r += 4) {
      a0 += bf2f(DT.s[r+0]) * dw[r+0];
      a1 += bf2f(DT.s[r+1]) * dw[r+1];
      a2 += bf2f(DT.s[r+2]) * dw[r+2];
      a3 += bf2f(DT.s[r+3]) * dw[r+3];
    }
    const float d = softplus_f(((a0 + a1) + (a2 + a3)) + bias);
    const float xv  = bf2f(x[m * DI + e]);
    const float dbx = d * xv;
    float dAv[DS];
    dA_generic(d, A2, dAv);
    float y = 0.f;
    #pragma unroll
    for (int n = 0; n < DS; n++) {
      h[n] = dAv[n] * h[n] + dbx * bf2f(BC.s[n]);
      y += h[n] * bf2f(BC.s[16 + n]);
    }
    const float yout = y + xv * dskip;
    if (MODE == 1) {
      yf[m * DI + e] = f2bf(yout);
    } else {
      const size_t mo = (size_t)b * SEQ + (SEQ - 1 - (c * ct + t));
      const size_t moi = mo * DI + e;
      yr[moi] = f2bf((bf2f(yf[moi]) + yout) * bf2f(szp[moi]));
    }
  }
}

// ---------------------------------------------------------------------------
extern "C" void kernel_launch(void* const* d_in, const int* in_sizes, int n_in,
                              void* d_out, int out_size, void* d_ws, size_t ws_size,
                              hipStream_t stream)
{
  (void)in_sizes; (void)n_in; (void)out_size;
  const float* u      = (const float*)d_in[0];
  const float* in_w   = (const float*)d_in[1];
  const float* out_w  = (const float*)d_in[2];
  const float* cw_f   = (const float*)d_in[3];
  const float* cb_f   = (const float*)d_in[4];
  const float* xw_f   = (const float*)d_in[5];
  const float* dtw_f  = (const float*)d_in[6];
  const float* dtb_f  = (const float*)d_in[7];
  const float* Alog_f = (const float*)d_in[8];
  const float* D_f    = (const float*)d_in[9];
  const float* cw_r   = (const float*)d_in[10];
  const float* cb_r   = (const float*)d_in[11];
  const float* xw_r   = (const float*)d_in[12];
  const float* dtw_r  = (const float*)d_in[13];
  const float* dtb_r  = (const float*)d_in[14];
  const float* Alog_r = (const float*)d_in[15];
  const float* D_r    = (const float*)d_in[16];

  const size_t mexe = (size_t)M_TOT * DI;          // 16.78M elements
  const size_t bc_bytes = (size_t)M_TOT * 32 * 4;  // 2.1 MB f32 BC per dir
  const size_t need_big =
      5 * (mexe * 2) + 2 * ((size_t)M_TOT * 64 * 2) + 2 * bc_bytes +
      (size_t)WU_TOT * 16 +
      (size_t)128 * NG * 4 + (size_t)128 * NCHAN * 4 + 64 * 256;
  const bool big = (ws_size >= need_big);
  const int nchunk = 64;               // legacy path: CT = 128
  const int ct = SEQ / nchunk;

  char* ws = (char*)d_ws;
  size_t off = 0;
  auto alloc = [&](size_t bytes) -> void* {
    void* p = ws + off;
    off += (bytes + 255) & ~(size_t)255;
    return p;
  };
  u16*   ubf   = (u16*)alloc(mexe * 2);            // bf16 u; dead after in_proj -> df
  u16*   xpre  = (u16*)alloc(mexe * 2);            // dead after conv -> yr
  u16*   xf    = (u16*)alloc(mexe * 2);            // x_f; in-place y_f / combined y
  u16*   xr    = (u16*)alloc(mexe * 2);
  u16*   xdblf = (u16*)alloc((size_t)M_TOT * 64 * 2);
  u16*   xdblr = (u16*)alloc((size_t)M_TOT * 64 * 2);
  float* bc32f = (float*)alloc(bc_bytes);          // f32 B/C operand, dir f
  float* bc32r = (float*)alloc(bc_bytes);
  u16*   wbf   = (u16*)alloc((size_t)WU_TOT * 16); // bf16 weight arena
  float* sumdP = (float*)alloc((size_t)128 * NG * 4);    // [0..63]=full, [64..127]=half
  float* bP    = (float*)alloc((size_t)128 * NCHAN * 4); // 128 sub-chunk slots
  u16*   dr    = big ? (u16*)alloc(mexe * 2) : nullptr;
  u16*   df    = ubf;                              // alias (u dead after in_proj)
  u16*   szb   = (u16*)d_out;                      // silu(z) in d_out (dead before out_proj)

  // weight arena sub-pointers (units of 8 elems = 16 B)
  u16* winb  = wbf;
  u16* xwbf  = wbf + (size_t)WU_INW * 8;
  u16* xwbr  = xwbf + (size_t)WU_XW * 8;
  u16* dtwbf = xwbr + (size_t)WU_XW * 8;
  u16* dtwbr = dtwbf + (size_t)WU_DTW * 8;
  u16* outwb = dtwbr + (size_t)WU_DTW * 8;

  dim3 blk(256);
  // 0) convert u + weights to bf16.  u has M_TOT*DM = 8.39M elems -> 4096 blocks.
  cvt_k<<<dim3((unsigned)((size_t)M_TOT * DM / 8 / 256)), blk, 0, stream>>>(u, ubf);
  cvtw_k<<<dim3(WU_TOT / 256), blk, 0, stream>>>(in_w, xw_f, xw_r, dtw_f, dtw_r, out_w, wbf);
  // 1) in_proj (BK=64)
  gemm_k<128, 64, 0, false><<<dim3(128, 16), blk, 0, stream>>>(
      ubf, nullptr, DM, winb, nullptr, DM, xpre, nullptr, szb, nullptr, nullptr, nullptr, 0);
  // 2) depthwise conv + silu, both dirs in one pass
  conv2_k<<<dim3(SEQ / (2 * CLT), B_SZ), blk, 0, stream>>>(
      xpre, cw_f, cb_f, cw_r, cb_r, xf, xr);
  // 3) xproj (dual, BK=64): xdbl = x @ xproj_w^T ; n>=32 also stored f32 to bc32
  gemm_k<64, 64, 1, true><<<dim3(128, 1, 2), blk, 0, stream>>>(
      xf, xr, DI, xwbf, xwbr, DI, xdblf, xdblr, bc32f, bc32r, nullptr, nullptr, 64);

  if (big) {
    // 4) delta (dual, BK=32 since K=32)
    gemm_k<128, 32, 2, true><<<dim3(128, 8, 2), blk, 0, stream>>>(
        xdblf, xdblr, 64, dtwbf, dtwbr, DTR, df, dr, nullptr, nullptr, dtb_f, dtb_r, DI);
    // 5) scan: A at CT=128 (64 chunks, half-carries), B emits h_in at 64-grain,
    //    C at CT=64 (128 chunks, max TLP)
    scanA2_k<128><<<dim3(8, 64, 4), dim3(128), 0, stream>>>(
        bc32f, bc32r, xf, xr, Alog_f, Alog_r, df, dr, sumdP, bP);
    scanB2_k<<<dim3(NCHAN / 256), blk, 0, stream>>>(sumdP, bP, Alog_f, Alog_r);
    scanC2_k<64><<<dim3(8, 128, 4), dim3(128), 0, stream>>>(
        bc32f, bc32r, xf, xr, Alog_f, Alog_r, df, dr, D_f, D_r, bP, xf, xpre);
    // 6) combine: yf = (yf + yr) * silu(z)
    comb_k<<<dim3((unsigned)(mexe / 8 / 256)), blk, 0, stream>>>(xf, xpre, szb);
    // 7) out_proj (BK=64) from combined xf
    gemm_k<128, 64, 3, false><<<dim3(128, 4), blk, 0, stream>>>(
        xf, nullptr, DI, outwb, nullptr, DI, d_out, nullptr, nullptr, nullptr, nullptr, nullptr, DM);
  } else {
    // legacy (low-ws) path
    scanA_k<<<dim3(4, nchunk, 4), blk, 0, stream>>>(
        xdblf, xdblr, xf, xr, Alog_f, Alog_r, dtw_f, dtw_r, dtb_f, dtb_r,
        sumdP, bP, ct);
    scanB_k<<<dim3(NCHAN / 256), blk, 0, stream>>>(sumdP, bP, Alog_f, Alog_r, nchunk);
    scanC_k<1><<<dim3(4, nchunk, 2), blk, 0, stream>>>(
        xdblf, xdblr, xf, xr, Alog_f, Alog_r, dtw_f, dtw_r, dtb_f, dtb_r,
        D_f, D_r, bP, xf, nullptr, nullptr, ct);
    scanC_k<2><<<dim3(4, nchunk, 2), blk, 0, stream>>>(
        xdblf, xdblr, xf, xr, Alog_f, Alog_r, dtw_f, dtw_r, dtb_f, dtb_r,
        D_f, D_r, bP, xf, xpre, szb, ct);
    gemm_k<128, 64, 3, false><<<dim3(128, 4), blk, 0, stream>>>(
        xpre, nullptr, DI, outwb, nullptr, DI, d_out, nullptr, nullptr, nullptr, nullptr, nullptr, DM);
  }
}